// Round 3
// baseline (16944.069 us; speedup 1.0000x reference)
//
#include <hip/hip_runtime.h>

// Persistent wavefront-pipelined LSTMP (3 layers), split-bf16 MFMA emulating fp32.
// Round 6: COALESCED COHERENT READS. Round-5 counters showed the weight stream
// gone (FETCH 15.2GB->0.9GB) but only -10% time: the step period is set by the
// exchange reads (~35 MB/step) issued as 8B agent-scope atomic loads -> ~4.4M
// uncoalesced LIC transactions/step (LIC rate-bound, MfmaUtil 5%).
// Fix: producers keep write-through atomic stores (cheap, ~200K/step), consumers
// switch to PLAIN 16B vector loads after an agent-scope ACQUIRE fence
// (invalidates L1+L2, so stale lines for the step-reused buffers are dropped and
// loads refetch 64B lines from LIC with L2 reuse across same-XCD blocks).
// 8x fewer LIC transactions on the read side; numerics bit-identical.

typedef short s16x4 __attribute__((ext_vector_type(4)));
typedef short s16x8 __attribute__((ext_vector_type(8)));
typedef float f32x4 __attribute__((ext_vector_type(4)));

#define MFMA16(a,b,c) __builtin_amdgcn_mfma_f32_16x16x32_bf16((a),(b),(c),0,0,0)

__device__ __forceinline__ unsigned short f2bf(float f) {
  unsigned int u = __builtin_bit_cast(unsigned int, f);
  u += 0x7FFFu + ((u >> 16) & 1u);          // RNE
  return (unsigned short)(u >> 16);
}
__device__ __forceinline__ float bf2f(unsigned short h) {
  unsigned int u = ((unsigned int)h) << 16;
  return __builtin_bit_cast(float, u);
}
__device__ __forceinline__ float fsig(float x)  { return __fdividef(1.0f, 1.0f + __expf(-x)); }
__device__ __forceinline__ float ftanh(float x) { return 1.0f - __fdividef(2.0f, 1.0f + __expf(2.0f * x)); }

// Write-through (LIC) 2B store.
__device__ __forceinline__ void cstore1(unsigned short* p, unsigned short v) {
  __hip_atomic_store(p, v, __ATOMIC_RELAXED, __HIP_MEMORY_SCOPE_AGENT);
}

// Agent-scope acquire: invalidate L1+L2 so plain loads refetch from LIC.
__device__ __forceinline__ void acq_agent() {
  __builtin_amdgcn_fence(__ATOMIC_ACQUIRE, "agent");
}

// Relaxed sense-counting grid barrier (192 blocks, 512 threads).
__device__ __forceinline__ void gbar(unsigned int* bar, unsigned int* rel, unsigned int seq) {
  __syncthreads();
  asm volatile("" ::: "memory");
  if (blockIdx.x == 0) {
    const int tid = threadIdx.x;
    if (tid > 0 && tid < 192) {
      while (__hip_atomic_load(&bar[tid * 16], __ATOMIC_RELAXED, __HIP_MEMORY_SCOPE_AGENT) != seq) {
        __builtin_amdgcn_s_sleep(1);
      }
    }
    __syncthreads();
    if (tid == 0) {
      __hip_atomic_store(rel, seq, __ATOMIC_RELAXED, __HIP_MEMORY_SCOPE_AGENT);
    }
  } else {
    if (threadIdx.x == 0) {
      __hip_atomic_store(&bar[blockIdx.x * 16], seq, __ATOMIC_RELAXED, __HIP_MEMORY_SCOPE_AGENT);
      while (__hip_atomic_load(rel, __ATOMIC_RELAXED, __HIP_MEMORY_SCOPE_AGENT) != seq) {
        __builtin_amdgcn_s_sleep(1);
      }
    }
    __syncthreads();
  }
  asm volatile("" ::: "memory");
}

__global__ __launch_bounds__(512, 2) void lstmp_persist(
    const float* __restrict__ x,
    const float* __restrict__ W0, const float* __restrict__ b0, const float* __restrict__ P0,
    const float* __restrict__ pi0, const float* __restrict__ pf0, const float* __restrict__ po0,
    const float* __restrict__ W1, const float* __restrict__ b1, const float* __restrict__ P1,
    const float* __restrict__ pi1, const float* __restrict__ pf1, const float* __restrict__ po1,
    const float* __restrict__ W2, const float* __restrict__ b2, const float* __restrict__ P2,
    const float* __restrict__ pi2, const float* __restrict__ pf2, const float* __restrict__ po2,
    float* __restrict__ out, unsigned char* __restrict__ ws)
{
  const int tid  = threadIdx.x;
  const int bid  = blockIdx.x;
  const int lane = tid & 63;
  const int wv   = tid >> 6;             // 0..7
  const int quad8 = (lane >> 4) * 8;
  const int nrow  = lane & 15;

  // ---- workspace carve ----
  unsigned int* bar   = (unsigned int*)ws;   // 192 slots * 16 uints (within 4096)
  unsigned int* rel   = bar + 4096;
  unsigned int* mflag = rel + 16;            // 3*64 flags
  unsigned short* xhi = (unsigned short*)(ws + 20480);
  unsigned short* xlo  = xhi  + 4096000;   // 500*32*256
  unsigned short* hhi  = xlo  + 4096000;   // 2 bufs * 3*32*512
  unsigned short* hlo  = hhi  + 98304;
  unsigned short* mhi  = hlo  + 98304;     // 3*32*1024
  unsigned short* mlo  = mhi  + 98304;

  const float* Wsrc[3] = {W0, W1, W2};
  const float* Psrc[3] = {P0, P1, P2};
  const float* Bsrc[3] = {b0, b1, b2};
  const float* PIs[3]  = {pi0, pi1, pi2};
  const float* PFs[3]  = {pf0, pf1, pf2};
  const float* POs[3]  = {po0, po1, po2};

  __shared__ float exch[8][4][512];  // 64 KB: per-wave partial sums
  __shared__ float c_lds[512];       // persistent cell state
  __shared__ float lds_pad[4096];    // 16 KB pad -> 82 KB total -> 1 block/CU
  ((volatile float*)lds_pad)[tid & 4095] = 0.0f;  // keep it allocated

  const unsigned int NT = 192u * 512u;
  const unsigned int gtid = (unsigned int)bid * 512u + (unsigned int)tid;

  // ---- fixed per-block roles (grid = 192, all workers) ----
  const int lA  = bid >> 6;          // layer 0..2
  const int utA = bid & 63;          // 16-unit tile (phase A)
  const int ptC = (bid & 63) >> 1;   // proj 16-col tile (phase C)
  const int mtC = bid & 1;           // batch half (phase C)

  const int nkbinA  = (lA == 0) ? 8   : 16;
  const int kinpadA = (lA == 0) ? 256 : 512;
  const int kbwA    = (lA == 0) ? 3   : 4;    // k-blocks per wave
  const int kwA     = (lA == 0) ? 752 : 1024;
  const int ninA    = (lA == 0) ? 240 : 512;
  const int kb0     = wv * kbwA;

  // ================= INIT: x staging + h zero =================
  for (unsigned int i = gtid; i < 4096000u; i += NT) {
    unsigned int k = i & 255u, tb = i >> 8;
    float v = (k < 240u) ? x[tb * 240u + k] : 0.0f;
    unsigned short h = f2bf(v);
    xhi[i] = h; xlo[i] = f2bf(v - bf2f(h));
  }
  for (unsigned int i = gtid; i < 98304u; i += NT) { hhi[i] = 0; hlo[i] = 0; }
  c_lds[tid] = 0.0f;

  // ================= register-resident weights =================
  s16x8 wgh[4][4], wgl[4][4];
  {
    const float* Wl = Wsrc[lA];
    #pragma unroll
    for (int j = 0; j < 4; ++j) {
      if (j < kbwA) {
        const int kbase = (kb0 + j) * 32 + quad8;
        #pragma unroll
        for (int g = 0; g < 4; ++g) {
          const size_t r = (size_t)((g * 64 + utA) * 16 + nrow);
          #pragma unroll
          for (int jj = 0; jj < 8; ++jj) {
            const int k = kbase + jj;
            float v;
            if (k < kinpadA) v = (lA == 0 && k >= 240) ? 0.0f : Wl[r * kwA + k];
            else             v = Wl[r * kwA + (k - kinpadA + ninA)];
            unsigned short h = f2bf(v);
            wgh[j][g][jj] = (short)h;
            wgl[j][g][jj] = (short)f2bf(v - bf2f(h));
          }
        }
      } else {
        #pragma unroll
        for (int g = 0; g < 4; ++g) { wgh[j][g] = (s16x8)0; wgl[j][g] = (s16x8)0; }
      }
    }
  }
  s16x8 wph[4], wpl[4];
  {
    const float* Pl = Psrc[lA];
    const size_t prow = (size_t)(ptC * 16 + nrow);
    #pragma unroll
    for (int j = 0; j < 4; ++j) {
      const int kbase = (wv * 4 + j) * 32 + quad8;
      #pragma unroll
      for (int jj = 0; jj < 8; ++jj) {
        float v = Pl[prow * 1024u + (size_t)(kbase + jj)];
        unsigned short h = f2bf(v);
        wph[j][jj] = (short)h;
        wpl[j][jj] = (short)f2bf(v - bf2f(h));
      }
    }
  }
  // Pointwise constants: this thread always handles (b=tid>>4, u=tid&15).
  const int uc = utA * 16 + (tid & 15);
  const float rbc = Bsrc[lA][uc];
  const float rbi = Bsrc[lA][1024 + uc];
  const float rbf = Bsrc[lA][2048 + uc];
  const float rbo = Bsrc[lA][3072 + uc];
  const float rpi = PIs[lA][uc];
  const float rpf = PFs[lA][uc];
  const float rpo = POs[lA][uc];

  unsigned int seq = 1;
  __builtin_amdgcn_fence(__ATOMIC_RELEASE, "agent");
  gbar(bar, rel, seq++);
  __builtin_amdgcn_fence(__ATOMIC_ACQUIRE, "agent");

  for (int s = 0; s < 502; ++s) {
    const int t = s - lA;
    const bool act = (t >= 0) && (t < 500);
    const int rbuf = (s + 1) & 1;    // h buffer written at step s-1
    const int wbuf = s & 1;          // h buffer written at step s

    if (act) {
      // Invalidate L1/L2: h/x lines cached in previous steps are stale
      // (producers wrote through to LIC). Plain loads below refetch lines.
      acq_agent();

      // ============ PHASE A: gates GEMM (8 waves split K, reg weights) ============
      f32x4 acc[4][2];
      #pragma unroll
      for (int g = 0; g < 4; ++g) { acc[g][0] = {0.f,0.f,0.f,0.f}; acc[g][1] = {0.f,0.f,0.f,0.f}; }

      const unsigned short* hbh = hhi + rbuf * 49152;
      const unsigned short* hbl = hlo + rbuf * 49152;

      #pragma unroll
      for (int j = 0; j < 4; ++j) {
        if (j < kbwA) {
          const int kb = kb0 + j;
          s16x8 fa0h, fa0l, fa1h, fa1l;
          if (kb < nkbinA) {
            if (lA == 0) {
              const unsigned short* ph = xhi + (size_t)(t * 32 + nrow) * 256 + kb * 32 + quad8;
              const unsigned short* pl = xlo + (size_t)(t * 32 + nrow) * 256 + kb * 32 + quad8;
              fa0h = *(const s16x8*)ph; fa1h = *(const s16x8*)(ph + 16 * 256);
              fa0l = *(const s16x8*)pl; fa1l = *(const s16x8*)(pl + 16 * 256);
            } else {
              const unsigned short* ph = hbh + (size_t)((lA - 1) * 32 + nrow) * 512 + kb * 32 + quad8;
              const unsigned short* pl = hbl + (size_t)((lA - 1) * 32 + nrow) * 512 + kb * 32 + quad8;
              fa0h = *(const s16x8*)ph; fa1h = *(const s16x8*)(ph + 16 * 512);
              fa0l = *(const s16x8*)pl; fa1l = *(const s16x8*)(pl + 16 * 512);
            }
          } else {
            const int ko = kb * 32 + quad8 - kinpadA;
            const unsigned short* ph = hbh + (size_t)(lA * 32 + nrow) * 512 + ko;
            const unsigned short* pl = hbl + (size_t)(lA * 32 + nrow) * 512 + ko;
            fa0h = *(const s16x8*)ph; fa1h = *(const s16x8*)(ph + 16 * 512);
            fa0l = *(const s16x8*)pl; fa1l = *(const s16x8*)(pl + 16 * 512);
          }
          #pragma unroll
          for (int g = 0; g < 4; ++g) {
            acc[g][0] = MFMA16(fa0h, wgh[j][g], acc[g][0]);
            acc[g][0] = MFMA16(fa0l, wgh[j][g], acc[g][0]);
            acc[g][0] = MFMA16(fa0h, wgl[j][g], acc[g][0]);
            acc[g][1] = MFMA16(fa1h, wgh[j][g], acc[g][1]);
            acc[g][1] = MFMA16(fa1l, wgh[j][g], acc[g][1]);
            acc[g][1] = MFMA16(fa1h, wgl[j][g], acc[g][1]);
          }
        }
      }
      #pragma unroll
      for (int g = 0; g < 4; ++g) {
        #pragma unroll
        for (int r = 0; r < 4; ++r) {
          const int m0 = (lane >> 4) * 4 + r;
          exch[wv][g][m0 * 16 + (lane & 15)]        = acc[g][0][r];
          exch[wv][g][(m0 + 16) * 16 + (lane & 15)] = acc[g][1][r];
        }
      }
      __syncthreads();

      // ---- fused pointwise: 512 threads, 1 (b,u) each, constants in regs ----
      {
        const int e = tid, b = tid >> 4;
        float sc = 0.f, si = 0.f, sf = 0.f, so = 0.f;
        #pragma unroll
        for (int w = 0; w < 8; ++w) {
          sc += exch[w][0][e]; si += exch[w][1][e];
          sf += exch[w][2][e]; so += exch[w][3][e];
        }
        const float cin = sc + rbc;
        const float gi  = si + rbi;
        const float gf  = sf + rbf;
        const float go  = so + rbo;
        const float cx  = c_lds[e];
        const float ig  = fsig(gi + rpi * cx);
        const float fg  = fsig(gf + rpf * cx);
        float cy = fg * cx + ig * ftanh(cin);
        cy = fminf(50.0f, fmaxf(-50.0f, cy));
        const float og = fsig(go + rpo * cy);
        const float mv = og * ftanh(cy);
        c_lds[e] = cy;
        const unsigned short mh = f2bf(mv);
        const size_t mi = (size_t)(lA * 32 + b) * 1024 + uc;
        cstore1(mhi + mi, mh);
        cstore1(mlo + mi, f2bf(mv - bf2f(mh)));
      }
      __syncthreads();   // drains each wave's vm stores before flag
      if (tid == 0) {
        __hip_atomic_store(&mflag[lA * 64 + utA], (unsigned int)(s + 1),
                           __ATOMIC_RELAXED, __HIP_MEMORY_SCOPE_AGENT);
      }

      // ============ PHASE C: projection (8 waves split K, reg weights) ============
      // wait for all 64 m-producers of this layer
      if (wv == 0) {
        const unsigned int want = (unsigned int)(s + 1);
        const unsigned int* fp = mflag + lA * 64 + lane;
        while (__hip_atomic_load(fp, __ATOMIC_RELAXED, __HIP_MEMORY_SCOPE_AGENT) != want) {
          __builtin_amdgcn_s_sleep(1);
        }
      }
      __syncthreads();
      // Invalidate: m lines (same addresses every step) must refetch from LIC.
      acq_agent();

      const unsigned short* mah = mhi + (size_t)(lA * 32 + mtC * 16 + nrow) * 1024;
      const unsigned short* mal = mlo + (size_t)(lA * 32 + mtC * 16 + nrow) * 1024;
      f32x4 pacc = {0.f, 0.f, 0.f, 0.f};
      #pragma unroll
      for (int j = 0; j < 4; ++j) {
        const int ko = (wv * 4 + j) * 32 + quad8;
        s16x8 fah = *(const s16x8*)(mah + ko);
        s16x8 fal = *(const s16x8*)(mal + ko);
        pacc = MFMA16(fah, wph[j], pacc);
        pacc = MFMA16(fal, wph[j], pacc);
        pacc = MFMA16(fah, wpl[j], pacc);
      }
      #pragma unroll
      for (int r = 0; r < 4; ++r) {
        exch[wv][0][((lane >> 4) * 4 + r) * 16 + (lane & 15)] = pacc[r];
      }
      __syncthreads();
      if (tid < 256) {
        float v = 0.f;
        #pragma unroll
        for (int w = 0; w < 8; ++w) v += exch[w][0][tid];
        const int b = mtC * 16 + (tid >> 4);
        const int p = ptC * 16 + (tid & 15);
        const size_t hidx = (size_t)wbuf * 49152 + (size_t)(lA * 32 + b) * 512 + p;
        const unsigned short hh = f2bf(v);
        cstore1(hhi + hidx, hh);
        cstore1(hlo + hidx, f2bf(v - bf2f(hh)));
        if (lA == 2) out[((size_t)t * 32 + b) * 512 + p] = v;
      }
    }
    gbar(bar, rel, seq++);
  }
}

extern "C" void kernel_launch(void* const* d_in, const int* in_sizes, int n_in,
                              void* d_out, int out_size, void* d_ws, size_t ws_size,
                              hipStream_t stream) {
  const float* x   = (const float*)d_in[0];
  const float* W0  = (const float*)d_in[1];
  const float* b0  = (const float*)d_in[2];
  const float* P0  = (const float*)d_in[3];
  const float* pi0 = (const float*)d_in[4];
  const float* pf0 = (const float*)d_in[5];
  const float* po0 = (const float*)d_in[6];
  const float* W1  = (const float*)d_in[7];
  const float* b1  = (const float*)d_in[8];
  const float* P1  = (const float*)d_in[9];
  const float* pi1 = (const float*)d_in[10];
  const float* pf1 = (const float*)d_in[11];
  const float* po1 = (const float*)d_in[12];
  const float* W2  = (const float*)d_in[13];
  const float* b2  = (const float*)d_in[14];
  const float* P2  = (const float*)d_in[15];
  const float* pi2 = (const float*)d_in[16];
  const float* pf2 = (const float*)d_in[17];
  const float* po2 = (const float*)d_in[18];

  hipLaunchKernelGGL(lstmp_persist, dim3(192), dim3(512), 0, stream,
                     x, W0, b0, P0, pi0, pf0, po0,
                     W1, b1, P1, pi1, pf1, po1,
                     W2, b2, P2, pi2, pf2, po2,
                     (float*)d_out, (unsigned char*)d_ws);
}

// Round 4
// 11563.120 us; speedup vs baseline: 1.4654x; 1.4654x over previous
//
#include <hip/hip_runtime.h>

// Persistent wavefront-pipelined LSTMP (3 layers), split-bf16 MFMA emulating fp32.
// Round 7: GBAR-FREE DATAFLOW. Round-6's fence experiment regressed (L2 inval
// serialization); round-2 counters showed the step period is a serial sync chain
// (MfmaUtil 5%, HBM 1.6%), dominated by the per-step global barrier (2 LIC round
// trips + 2x global skew every step). This round removes the per-step gbar:
// blocks free-run their own t=0..499 loop, synchronized only by monotone flags:
//   hflag[l][tile]=t+1 after h[t] store; phase A waits hflag[l]>=t (recurrent)
//   and hflag[l-1]>=t+1 (input). mflag as before but >= (monotone).
//   h is 4-deep buffered (mod-4); phase C back-pressure: mflag[l+1]>=t-3 keeps
//   any layer <=3 beats ahead of its downstream reader (deadlock-free, acyclic).
// Producer->flag ordering mechanism unchanged (atomic stores -> __syncthreads
// drain -> flag store), proven in rounds 0-2. Weights stay register-resident.

typedef short s16x4 __attribute__((ext_vector_type(4)));
typedef short s16x8 __attribute__((ext_vector_type(8)));
typedef float f32x4 __attribute__((ext_vector_type(4)));

#define MFMA16(a,b,c) __builtin_amdgcn_mfma_f32_16x16x32_bf16((a),(b),(c),0,0,0)

__device__ __forceinline__ unsigned short f2bf(float f) {
  unsigned int u = __builtin_bit_cast(unsigned int, f);
  u += 0x7FFFu + ((u >> 16) & 1u);          // RNE
  return (unsigned short)(u >> 16);
}
__device__ __forceinline__ float bf2f(unsigned short h) {
  unsigned int u = ((unsigned int)h) << 16;
  return __builtin_bit_cast(float, u);
}
__device__ __forceinline__ float fsig(float x)  { return __fdividef(1.0f, 1.0f + __expf(-x)); }
__device__ __forceinline__ float ftanh(float x) { return 1.0f - __fdividef(2.0f, 1.0f + __expf(2.0f * x)); }

// Coherent (LIC) 16B read as two relaxed agent-scope 8B atomic loads.
__device__ __forceinline__ s16x8 cload(const unsigned short* p) {
  unsigned long long a = __hip_atomic_load((unsigned long long*)p,       __ATOMIC_RELAXED, __HIP_MEMORY_SCOPE_AGENT);
  unsigned long long b = __hip_atomic_load((unsigned long long*)(p + 4), __ATOMIC_RELAXED, __HIP_MEMORY_SCOPE_AGENT);
  s16x4 x = __builtin_bit_cast(s16x4, a);
  s16x4 y = __builtin_bit_cast(s16x4, b);
  s16x8 r = {x[0], x[1], x[2], x[3], y[0], y[1], y[2], y[3]};
  return r;
}
__device__ __forceinline__ void cstore1(unsigned short* p, unsigned short v) {
  __hip_atomic_store(p, v, __ATOMIC_RELAXED, __HIP_MEMORY_SCOPE_AGENT);
}

// Relaxed sense-counting grid barrier (192 blocks, 512 threads) — INIT ONLY.
__device__ __forceinline__ void gbar(unsigned int* bar, unsigned int* rel, unsigned int seq) {
  __syncthreads();
  asm volatile("" ::: "memory");
  if (blockIdx.x == 0) {
    const int tid = threadIdx.x;
    if (tid > 0 && tid < 192) {
      while (__hip_atomic_load(&bar[tid * 16], __ATOMIC_RELAXED, __HIP_MEMORY_SCOPE_AGENT) != seq) {
        __builtin_amdgcn_s_sleep(1);
      }
    }
    __syncthreads();
    if (tid == 0) {
      __hip_atomic_store(rel, seq, __ATOMIC_RELAXED, __HIP_MEMORY_SCOPE_AGENT);
    }
  } else {
    if (threadIdx.x == 0) {
      __hip_atomic_store(&bar[blockIdx.x * 16], seq, __ATOMIC_RELAXED, __HIP_MEMORY_SCOPE_AGENT);
      while (__hip_atomic_load(rel, __ATOMIC_RELAXED, __HIP_MEMORY_SCOPE_AGENT) != seq) {
        __builtin_amdgcn_s_sleep(1);
      }
    }
    __syncthreads();
  }
  asm volatile("" ::: "memory");
}

__global__ __launch_bounds__(512, 2) void lstmp_persist(
    const float* __restrict__ x,
    const float* __restrict__ W0, const float* __restrict__ b0, const float* __restrict__ P0,
    const float* __restrict__ pi0, const float* __restrict__ pf0, const float* __restrict__ po0,
    const float* __restrict__ W1, const float* __restrict__ b1, const float* __restrict__ P1,
    const float* __restrict__ pi1, const float* __restrict__ pf1, const float* __restrict__ po1,
    const float* __restrict__ W2, const float* __restrict__ b2, const float* __restrict__ P2,
    const float* __restrict__ pi2, const float* __restrict__ pf2, const float* __restrict__ po2,
    float* __restrict__ out, unsigned char* __restrict__ ws)
{
  const int tid  = threadIdx.x;
  const int bid  = blockIdx.x;
  const int lane = tid & 63;
  const int wv   = tid >> 6;             // 0..7
  const int quad8 = (lane >> 4) * 8;
  const int nrow  = lane & 15;

  // ---- workspace carve ----
  unsigned int* bar   = (unsigned int*)ws;   // 192 slots * 16 uints (init gbar)
  unsigned int* rel   = bar + 4096;
  unsigned int* mflag = rel + 16;            // 3*64 monotone flags
  unsigned int* hflag = mflag + 192;         // 3*64 monotone flags
  unsigned short* xhi = (unsigned short*)(ws + 20480);
  unsigned short* xlo  = xhi  + 4096000;   // 500*32*256
  unsigned short* hhi  = xlo  + 4096000;   // 4 bufs * 3*32*512 = 196608
  unsigned short* hlo  = hhi  + 196608;
  unsigned short* mhi  = hlo  + 196608;    // 3*32*1024
  unsigned short* mlo  = mhi  + 98304;

  const float* Wsrc[3] = {W0, W1, W2};
  const float* Psrc[3] = {P0, P1, P2};
  const float* Bsrc[3] = {b0, b1, b2};
  const float* PIs[3]  = {pi0, pi1, pi2};
  const float* PFs[3]  = {pf0, pf1, pf2};
  const float* POs[3]  = {po0, po1, po2};

  __shared__ float exch[8][4][512];  // 64 KB: per-wave partial sums
  __shared__ float c_lds[512];       // persistent cell state
  __shared__ float lds_pad[4096];    // 16 KB pad -> 82 KB total -> 1 block/CU
  ((volatile float*)lds_pad)[tid & 4095] = 0.0f;  // keep it allocated

  const unsigned int NT = 192u * 512u;
  const unsigned int gtid = (unsigned int)bid * 512u + (unsigned int)tid;

  // ---- fixed per-block roles (grid = 192, all workers) ----
  const int lA  = bid >> 6;          // layer 0..2
  const int utA = bid & 63;          // 16-unit tile (phase A)
  const int ptC = (bid & 63) >> 1;   // proj 16-col tile (phase C)
  const int mtC = bid & 1;           // batch half (phase C)

  const int nkbinA  = (lA == 0) ? 8   : 16;
  const int kinpadA = (lA == 0) ? 256 : 512;
  const int kbwA    = (lA == 0) ? 3   : 4;    // k-blocks per wave
  const int kwA     = (lA == 0) ? 752 : 1024;
  const int ninA    = (lA == 0) ? 240 : 512;
  const int kb0     = wv * kbwA;

  // ================= INIT: x staging + h zero + flag zero =================
  for (unsigned int i = gtid; i < 4096000u; i += NT) {
    unsigned int k = i & 255u, tb = i >> 8;
    float v = (k < 240u) ? x[tb * 240u + k] : 0.0f;
    unsigned short h = f2bf(v);
    xhi[i] = h; xlo[i] = f2bf(v - bf2f(h));
  }
  for (unsigned int i = gtid; i < 196608u; i += NT) { hhi[i] = 0; hlo[i] = 0; }
  if (gtid < 384u) mflag[gtid] = 0u;   // mflag + hflag contiguous
  c_lds[tid] = 0.0f;

  // ================= register-resident weights =================
  s16x8 wgh[4][4], wgl[4][4];
  {
    const float* Wl = Wsrc[lA];
    #pragma unroll
    for (int j = 0; j < 4; ++j) {
      if (j < kbwA) {
        const int kbase = (kb0 + j) * 32 + quad8;
        #pragma unroll
        for (int g = 0; g < 4; ++g) {
          const size_t r = (size_t)((g * 64 + utA) * 16 + nrow);
          #pragma unroll
          for (int jj = 0; jj < 8; ++jj) {
            const int k = kbase + jj;
            float v;
            if (k < kinpadA) v = (lA == 0 && k >= 240) ? 0.0f : Wl[r * kwA + k];
            else             v = Wl[r * kwA + (k - kinpadA + ninA)];
            unsigned short h = f2bf(v);
            wgh[j][g][jj] = (short)h;
            wgl[j][g][jj] = (short)f2bf(v - bf2f(h));
          }
        }
      } else {
        #pragma unroll
        for (int g = 0; g < 4; ++g) { wgh[j][g] = (s16x8)0; wgl[j][g] = (s16x8)0; }
      }
    }
  }
  s16x8 wph[4], wpl[4];
  {
    const float* Pl = Psrc[lA];
    const size_t prow = (size_t)(ptC * 16 + nrow);
    #pragma unroll
    for (int j = 0; j < 4; ++j) {
      const int kbase = (wv * 4 + j) * 32 + quad8;
      #pragma unroll
      for (int jj = 0; jj < 8; ++jj) {
        float v = Pl[prow * 1024u + (size_t)(kbase + jj)];
        unsigned short h = f2bf(v);
        wph[j][jj] = (short)h;
        wpl[j][jj] = (short)f2bf(v - bf2f(h));
      }
    }
  }
  // Pointwise constants: this thread always handles (b=tid>>4, u=tid&15).
  const int uc = utA * 16 + (tid & 15);
  const float rbc = Bsrc[lA][uc];
  const float rbi = Bsrc[lA][1024 + uc];
  const float rbf = Bsrc[lA][2048 + uc];
  const float rbo = Bsrc[lA][3072 + uc];
  const float rpi = PIs[lA][uc];
  const float rpf = PFs[lA][uc];
  const float rpo = POs[lA][uc];

  // One-time init barrier (also writes back dirty L2 so x staging is visible).
  __builtin_amdgcn_fence(__ATOMIC_RELEASE, "agent");
  gbar(bar, rel, 1u);
  __builtin_amdgcn_fence(__ATOMIC_ACQUIRE, "agent");

  // ================= free-running per-layer local time =================
  for (int t = 0; t < 500; ++t) {
    // ---- input-ready waits (monotone flags) ----
    if (wv == 0) {
      // recurrent h_l[t-1]: flag value t (trivially true at t=0)
      const unsigned int want = (unsigned int)t;
      const unsigned int* fp = hflag + lA * 64 + lane;
      while (__hip_atomic_load(fp, __ATOMIC_RELAXED, __HIP_MEMORY_SCOPE_AGENT) < want) {
        __builtin_amdgcn_s_sleep(1);
      }
    } else if (wv == 1 && lA > 0) {
      // input h_{l-1}[t]: flag value t+1
      const unsigned int want = (unsigned int)(t + 1);
      const unsigned int* fp = hflag + (lA - 1) * 64 + lane;
      while (__hip_atomic_load(fp, __ATOMIC_RELAXED, __HIP_MEMORY_SCOPE_AGENT) < want) {
        __builtin_amdgcn_s_sleep(1);
      }
    }
    __syncthreads();

    const unsigned short* hRecH = hhi + (size_t)(((t + 3) & 3) * 49152 + lA * 16384);
    const unsigned short* hRecL = hlo + (size_t)(((t + 3) & 3) * 49152 + lA * 16384);
    const unsigned short* hInH  = hhi + (size_t)((t & 3) * 49152 + (lA - 1) * 16384);
    const unsigned short* hInL  = hlo + (size_t)((t & 3) * 49152 + (lA - 1) * 16384);

    // ============ PHASE A: gates GEMM (8 waves split K, reg weights) ============
    f32x4 acc[4][2];
    #pragma unroll
    for (int g = 0; g < 4; ++g) { acc[g][0] = {0.f,0.f,0.f,0.f}; acc[g][1] = {0.f,0.f,0.f,0.f}; }

    #pragma unroll
    for (int j = 0; j < 4; ++j) {
      if (j < kbwA) {
        const int kb = kb0 + j;
        s16x8 fa0h, fa0l, fa1h, fa1l;
        if (kb < nkbinA) {
          if (lA == 0) {
            const unsigned short* ph = xhi + (size_t)(t * 32 + nrow) * 256 + kb * 32 + quad8;
            const unsigned short* pl = xlo + (size_t)(t * 32 + nrow) * 256 + kb * 32 + quad8;
            fa0h = *(const s16x8*)ph; fa1h = *(const s16x8*)(ph + 16 * 256);
            fa0l = *(const s16x8*)pl; fa1l = *(const s16x8*)(pl + 16 * 256);
          } else {
            const unsigned short* ph = hInH + (size_t)nrow * 512 + kb * 32 + quad8;
            const unsigned short* pl = hInL + (size_t)nrow * 512 + kb * 32 + quad8;
            fa0h = cload(ph); fa1h = cload(ph + 16 * 512);
            fa0l = cload(pl); fa1l = cload(pl + 16 * 512);
          }
        } else {
          const int ko = kb * 32 + quad8 - kinpadA;
          const unsigned short* ph = hRecH + (size_t)nrow * 512 + ko;
          const unsigned short* pl = hRecL + (size_t)nrow * 512 + ko;
          fa0h = cload(ph); fa1h = cload(ph + 16 * 512);
          fa0l = cload(pl); fa1l = cload(pl + 16 * 512);
        }
        #pragma unroll
        for (int g = 0; g < 4; ++g) {
          acc[g][0] = MFMA16(fa0h, wgh[j][g], acc[g][0]);
          acc[g][0] = MFMA16(fa0l, wgh[j][g], acc[g][0]);
          acc[g][0] = MFMA16(fa0h, wgl[j][g], acc[g][0]);
          acc[g][1] = MFMA16(fa1h, wgh[j][g], acc[g][1]);
          acc[g][1] = MFMA16(fa1l, wgh[j][g], acc[g][1]);
          acc[g][1] = MFMA16(fa1h, wgl[j][g], acc[g][1]);
        }
      }
    }
    #pragma unroll
    for (int g = 0; g < 4; ++g) {
      #pragma unroll
      for (int r = 0; r < 4; ++r) {
        const int m0 = (lane >> 4) * 4 + r;
        exch[wv][g][m0 * 16 + (lane & 15)]        = acc[g][0][r];
        exch[wv][g][(m0 + 16) * 16 + (lane & 15)] = acc[g][1][r];
      }
    }
    __syncthreads();

    // ---- fused pointwise: 512 threads, 1 (b,u) each, constants in regs ----
    {
      const int e = tid, b = tid >> 4;
      float sc = 0.f, si = 0.f, sf = 0.f, so = 0.f;
      #pragma unroll
      for (int w = 0; w < 8; ++w) {
        sc += exch[w][0][e]; si += exch[w][1][e];
        sf += exch[w][2][e]; so += exch[w][3][e];
      }
      const float cin = sc + rbc;
      const float gi  = si + rbi;
      const float gf  = sf + rbf;
      const float go  = so + rbo;
      const float cx  = c_lds[e];
      const float ig  = fsig(gi + rpi * cx);
      const float fg  = fsig(gf + rpf * cx);
      float cy = fg * cx + ig * ftanh(cin);
      cy = fminf(50.0f, fmaxf(-50.0f, cy));
      const float og = fsig(go + rpo * cy);
      const float mv = og * ftanh(cy);
      c_lds[e] = cy;
      const unsigned short mh = f2bf(mv);
      const size_t mi = (size_t)(lA * 32 + b) * 1024 + uc;
      cstore1(mhi + mi, mh);
      cstore1(mlo + mi, f2bf(mv - bf2f(mh)));
    }
    __syncthreads();   // drains each wave's vm stores before flag
    if (tid == 0) {
      __hip_atomic_store(&mflag[lA * 64 + utA], (unsigned int)(t + 1),
                         __ATOMIC_RELAXED, __HIP_MEMORY_SCOPE_AGENT);
    }

    // ============ PHASE C: projection (8 waves split K, reg weights) ============
    if (wv == 0) {
      // all 64 m-producers of this layer at local time t
      const unsigned int want = (unsigned int)(t + 1);
      const unsigned int* fp = mflag + lA * 64 + lane;
      while (__hip_atomic_load(fp, __ATOMIC_RELAXED, __HIP_MEMORY_SCOPE_AGENT) < want) {
        __builtin_amdgcn_s_sleep(1);
      }
    } else if (wv == 1 && lA < 2 && t >= 4) {
      // back-pressure: downstream layer must have finished phase A of t-4
      // (last reader of the h buffer slot we are about to overwrite)
      const unsigned int want = (unsigned int)(t - 3);
      const unsigned int* fp = mflag + (lA + 1) * 64 + lane;
      while (__hip_atomic_load(fp, __ATOMIC_RELAXED, __HIP_MEMORY_SCOPE_AGENT) < want) {
        __builtin_amdgcn_s_sleep(1);
      }
    }
    __syncthreads();

    const unsigned short* mah = mhi + (size_t)(lA * 32 + mtC * 16 + nrow) * 1024;
    const unsigned short* mal = mlo + (size_t)(lA * 32 + mtC * 16 + nrow) * 1024;
    f32x4 pacc = {0.f, 0.f, 0.f, 0.f};
    #pragma unroll
    for (int j = 0; j < 4; ++j) {
      const int ko = (wv * 4 + j) * 32 + quad8;
      s16x8 fah = cload(mah + ko);
      s16x8 fal = cload(mal + ko);
      pacc = MFMA16(fah, wph[j], pacc);
      pacc = MFMA16(fal, wph[j], pacc);
      pacc = MFMA16(fah, wpl[j], pacc);
    }
    #pragma unroll
    for (int r = 0; r < 4; ++r) {
      exch[wv][0][((lane >> 4) * 4 + r) * 16 + (lane & 15)] = pacc[r];
    }
    __syncthreads();
    if (tid < 256) {
      float v = 0.f;
      #pragma unroll
      for (int w = 0; w < 8; ++w) v += exch[w][0][tid];
      const int b = mtC * 16 + (tid >> 4);
      const int p = ptC * 16 + (tid & 15);
      const size_t hidx = (size_t)((t & 3) * 49152 + lA * 16384) + (size_t)b * 512 + p;
      const unsigned short hh = f2bf(v);
      cstore1(hhi + hidx, hh);
      cstore1(hlo + hidx, f2bf(v - bf2f(hh)));
      if (lA == 2) out[((size_t)t * 32 + b) * 512 + p] = v;
    }
    __syncthreads();   // drains h stores before flag
    if (tid == 0) {
      __hip_atomic_store(&hflag[lA * 64 + (bid & 63)], (unsigned int)(t + 1),
                         __ATOMIC_RELAXED, __HIP_MEMORY_SCOPE_AGENT);
    }
  }
}

extern "C" void kernel_launch(void* const* d_in, const int* in_sizes, int n_in,
                              void* d_out, int out_size, void* d_ws, size_t ws_size,
                              hipStream_t stream) {
  const float* x   = (const float*)d_in[0];
  const float* W0  = (const float*)d_in[1];
  const float* b0  = (const float*)d_in[2];
  const float* P0  = (const float*)d_in[3];
  const float* pi0 = (const float*)d_in[4];
  const float* pf0 = (const float*)d_in[5];
  const float* po0 = (const float*)d_in[6];
  const float* W1  = (const float*)d_in[7];
  const float* b1  = (const float*)d_in[8];
  const float* P1  = (const float*)d_in[9];
  const float* pi1 = (const float*)d_in[10];
  const float* pf1 = (const float*)d_in[11];
  const float* po1 = (const float*)d_in[12];
  const float* W2  = (const float*)d_in[13];
  const float* b2  = (const float*)d_in[14];
  const float* P2  = (const float*)d_in[15];
  const float* pi2 = (const float*)d_in[16];
  const float* pf2 = (const float*)d_in[17];
  const float* po2 = (const float*)d_in[18];

  hipLaunchKernelGGL(lstmp_persist, dim3(192), dim3(512), 0, stream,
                     x, W0, b0, P0, pi0, pf0, po0,
                     W1, b1, P1, pi1, pf1, po1,
                     W2, b2, P2, pi2, pf2, po2,
                     (float*)d_out, (unsigned char*)d_ws);
}

// Round 6
// 8976.063 us; speedup vs baseline: 1.8877x; 1.2882x over previous
//
#include <hip/hip_runtime.h>

// Persistent wavefront-pipelined LSTMP (3 layers), split-bf16 MFMA emulating fp32.
// Round 8: COALESCED BYPASS READS (fence-free). Evidence r2/r3/r4: beat time is
// set by ~4M uncoalesced 8B agent-atomic LIC read transactions per step (36 MB of
// h/m broadcast re-reads), not by sync hops (r4: flags-only was WORSE than gbar)
// and not by HBM (r2: 1.6%). r3's fence+inval fix regressed on fence cost, not
// theory. Fix here: replace 8B atomic cloads with inline-asm
// `global_load_dwordx4 ... sc1` (device-scope: bypasses L1 + per-XCD L2, reads
// coherently from LIC — same semantics as the atomic path, but 16B/lane and
// wave-coalesced into 64B-line transactions, ~8x fewer LIC requests).
// Batch-issue all fragments, one s_waitcnt vmcnt(0) + sched_barrier(0) (rule #18)
// before the MFMA cluster. Structure = round-2 skeleton (gbar + mflag, 2-buf h),
// register-resident weights. MFMA order unchanged -> bit-identical numerics.

typedef short s16x4 __attribute__((ext_vector_type(4)));
typedef short s16x8 __attribute__((ext_vector_type(8)));
typedef float f32x4 __attribute__((ext_vector_type(4)));

#define MFMA16(a,b,c) __builtin_amdgcn_mfma_f32_16x16x32_bf16((a),(b),(c),0,0,0)

__device__ __forceinline__ unsigned short f2bf(float f) {
  unsigned int u = __builtin_bit_cast(unsigned int, f);
  u += 0x7FFFu + ((u >> 16) & 1u);          // RNE
  return (unsigned short)(u >> 16);
}
__device__ __forceinline__ float bf2f(unsigned short h) {
  unsigned int u = ((unsigned int)h) << 16;
  return __builtin_bit_cast(float, u);
}
__device__ __forceinline__ float fsig(float x)  { return __fdividef(1.0f, 1.0f + __expf(-x)); }
__device__ __forceinline__ float ftanh(float x) { return 1.0f - __fdividef(2.0f, 1.0f + __expf(2.0f * x)); }

// Device-scope (LIC-coherent) 16B load: bypasses L1 and per-XCD L2 via sc1.
// NOT complete until a subsequent vmcnt wait — use bwait() before consuming.
__device__ __forceinline__ void bload16(s16x8* dst, const unsigned short* p) {
  asm volatile("global_load_dwordx4 %0, %1, off sc1"
               : "=v"(*dst) : "v"(p) : "memory");
}
__device__ __forceinline__ void bwait() {
  asm volatile("s_waitcnt vmcnt(0)" ::: "memory");
  __builtin_amdgcn_sched_barrier(0);   // rule #18: stop MFMA hoist past waitcnt
}

// Write-through (LIC) 2B store.
__device__ __forceinline__ void cstore1(unsigned short* p, unsigned short v) {
  __hip_atomic_store(p, v, __ATOMIC_RELAXED, __HIP_MEMORY_SCOPE_AGENT);
}

// Relaxed sense-counting grid barrier (192 blocks, 512 threads).
__device__ __forceinline__ void gbar(unsigned int* bar, unsigned int* rel, unsigned int seq) {
  __syncthreads();
  asm volatile("" ::: "memory");
  if (blockIdx.x == 0) {
    const int tid = threadIdx.x;
    if (tid > 0 && tid < 192) {
      while (__hip_atomic_load(&bar[tid * 16], __ATOMIC_RELAXED, __HIP_MEMORY_SCOPE_AGENT) != seq) {
        __builtin_amdgcn_s_sleep(1);
      }
    }
    __syncthreads();
    if (tid == 0) {
      __hip_atomic_store(rel, seq, __ATOMIC_RELAXED, __HIP_MEMORY_SCOPE_AGENT);
    }
  } else {
    if (threadIdx.x == 0) {
      __hip_atomic_store(&bar[blockIdx.x * 16], seq, __ATOMIC_RELAXED, __HIP_MEMORY_SCOPE_AGENT);
      while (__hip_atomic_load(rel, __ATOMIC_RELAXED, __HIP_MEMORY_SCOPE_AGENT) != seq) {
        __builtin_amdgcn_s_sleep(1);
      }
    }
    __syncthreads();
  }
  asm volatile("" ::: "memory");
}

__global__ __launch_bounds__(512, 2) void lstmp_persist(
    const float* __restrict__ x,
    const float* __restrict__ W0, const float* __restrict__ b0, const float* __restrict__ P0,
    const float* __restrict__ pi0, const float* __restrict__ pf0, const float* __restrict__ po0,
    const float* __restrict__ W1, const float* __restrict__ b1, const float* __restrict__ P1,
    const float* __restrict__ pi1, const float* __restrict__ pf1, const float* __restrict__ po1,
    const float* __restrict__ W2, const float* __restrict__ b2, const float* __restrict__ P2,
    const float* __restrict__ pi2, const float* __restrict__ pf2, const float* __restrict__ po2,
    float* __restrict__ out, unsigned char* __restrict__ ws)
{
  const int tid  = threadIdx.x;
  const int bid  = blockIdx.x;
  const int lane = tid & 63;
  const int wv   = tid >> 6;             // 0..7
  const int quad8 = (lane >> 4) * 8;
  const int nrow  = lane & 15;

  // ---- workspace carve ----
  unsigned int* bar   = (unsigned int*)ws;   // 192 slots * 16 uints (within 4096)
  unsigned int* rel   = bar + 4096;
  unsigned int* mflag = rel + 16;            // 3*64 flags
  unsigned short* xhi = (unsigned short*)(ws + 20480);
  unsigned short* xlo  = xhi  + 4096000;   // 500*32*256
  unsigned short* hhi  = xlo  + 4096000;   // 2 bufs * 3*32*512
  unsigned short* hlo  = hhi  + 98304;
  unsigned short* mhi  = hlo  + 98304;     // 3*32*1024
  unsigned short* mlo  = mhi  + 98304;

  const float* Wsrc[3] = {W0, W1, W2};
  const float* Psrc[3] = {P0, P1, P2};
  const float* Bsrc[3] = {b0, b1, b2};
  const float* PIs[3]  = {pi0, pi1, pi2};
  const float* PFs[3]  = {pf0, pf1, pf2};
  const float* POs[3]  = {po0, po1, po2};

  __shared__ float exch[8][4][512];  // 64 KB: per-wave partial sums
  __shared__ float c_lds[512];       // persistent cell state
  __shared__ float lds_pad[4096];    // 16 KB pad -> 82 KB total -> 1 block/CU
  ((volatile float*)lds_pad)[tid & 4095] = 0.0f;  // keep it allocated

  const unsigned int NT = 192u * 512u;
  const unsigned int gtid = (unsigned int)bid * 512u + (unsigned int)tid;

  // ---- fixed per-block roles (grid = 192, all workers) ----
  const int lA  = bid >> 6;          // layer 0..2
  const int utA = bid & 63;          // 16-unit tile (phase A)
  const int ptC = (bid & 63) >> 1;   // proj 16-col tile (phase C)
  const int mtC = bid & 1;           // batch half (phase C)

  const int nkbinA  = (lA == 0) ? 8   : 16;
  const int kinpadA = (lA == 0) ? 256 : 512;
  const int kbwA    = (lA == 0) ? 3   : 4;    // k-blocks per wave
  const int kwA     = (lA == 0) ? 752 : 1024;
  const int ninA    = (lA == 0) ? 240 : 512;
  const int kb0     = wv * kbwA;

  // ================= INIT: x staging + h zero =================
  for (unsigned int i = gtid; i < 4096000u; i += NT) {
    unsigned int k = i & 255u, tb = i >> 8;
    float v = (k < 240u) ? x[tb * 240u + k] : 0.0f;
    unsigned short h = f2bf(v);
    xhi[i] = h; xlo[i] = f2bf(v - bf2f(h));
  }
  for (unsigned int i = gtid; i < 98304u; i += NT) { hhi[i] = 0; hlo[i] = 0; }
  c_lds[tid] = 0.0f;

  // ================= register-resident weights =================
  s16x8 wgh[4][4], wgl[4][4];
  {
    const float* Wl = Wsrc[lA];
    #pragma unroll
    for (int j = 0; j < 4; ++j) {
      if (j < kbwA) {
        const int kbase = (kb0 + j) * 32 + quad8;
        #pragma unroll
        for (int g = 0; g < 4; ++g) {
          const size_t r = (size_t)((g * 64 + utA) * 16 + nrow);
          #pragma unroll
          for (int jj = 0; jj < 8; ++jj) {
            const int k = kbase + jj;
            float v;
            if (k < kinpadA) v = (lA == 0 && k >= 240) ? 0.0f : Wl[r * kwA + k];
            else             v = Wl[r * kwA + (k - kinpadA + ninA)];
            unsigned short h = f2bf(v);
            wgh[j][g][jj] = (short)h;
            wgl[j][g][jj] = (short)f2bf(v - bf2f(h));
          }
        }
      } else {
        #pragma unroll
        for (int g = 0; g < 4; ++g) { wgh[j][g] = (s16x8)0; wgl[j][g] = (s16x8)0; }
      }
    }
  }
  s16x8 wph[4], wpl[4];
  {
    const float* Pl = Psrc[lA];
    const size_t prow = (size_t)(ptC * 16 + nrow);
    #pragma unroll
    for (int j = 0; j < 4; ++j) {
      const int kbase = (wv * 4 + j) * 32 + quad8;
      #pragma unroll
      for (int jj = 0; jj < 8; ++jj) {
        float v = Pl[prow * 1024u + (size_t)(kbase + jj)];
        unsigned short h = f2bf(v);
        wph[j][jj] = (short)h;
        wpl[j][jj] = (short)f2bf(v - bf2f(h));
      }
    }
  }
  // Pointwise constants: this thread always handles (b=tid>>4, u=tid&15).
  const int uc = utA * 16 + (tid & 15);
  const float rbc = Bsrc[lA][uc];
  const float rbi = Bsrc[lA][1024 + uc];
  const float rbf = Bsrc[lA][2048 + uc];
  const float rbo = Bsrc[lA][3072 + uc];
  const float rpi = PIs[lA][uc];
  const float rpf = PFs[lA][uc];
  const float rpo = POs[lA][uc];

  unsigned int seq = 1;
  __builtin_amdgcn_fence(__ATOMIC_RELEASE, "agent");
  gbar(bar, rel, seq++);
  __builtin_amdgcn_fence(__ATOMIC_ACQUIRE, "agent");

  for (int s = 0; s < 502; ++s) {
    const int t = s - lA;
    const bool act = (t >= 0) && (t < 500);
    const int rbuf = (s + 1) & 1;    // h buffer written at step s-1
    const int wbuf = s & 1;          // h buffer written at step s

    if (act) {
      // ============ PHASE A: gates GEMM (8 waves split K, reg weights) ============
      const unsigned short* hbh = hhi + rbuf * 49152;
      const unsigned short* hbl = hlo + rbuf * 49152;

      // ---- batch-issue all A-fragment loads (bypass sc1), then one wait ----
      s16x8 fh0[4], fl0[4], fh1[4], fl1[4];
      #pragma unroll
      for (int j = 0; j < 4; ++j) {
        if (j < kbwA) {
          const int kb = kb0 + j;
          if (kb < nkbinA) {
            if (lA == 0) {
              const unsigned short* ph = xhi + (size_t)(t * 32 + nrow) * 256 + kb * 32 + quad8;
              const unsigned short* pl = xlo + (size_t)(t * 32 + nrow) * 256 + kb * 32 + quad8;
              fh0[j] = *(const s16x8*)ph; fh1[j] = *(const s16x8*)(ph + 16 * 256);
              fl0[j] = *(const s16x8*)pl; fl1[j] = *(const s16x8*)(pl + 16 * 256);
            } else {
              const unsigned short* ph = hbh + (size_t)((lA - 1) * 32 + nrow) * 512 + kb * 32 + quad8;
              const unsigned short* pl = hbl + (size_t)((lA - 1) * 32 + nrow) * 512 + kb * 32 + quad8;
              bload16(&fh0[j], ph); bload16(&fh1[j], ph + 16 * 512);
              bload16(&fl0[j], pl); bload16(&fl1[j], pl + 16 * 512);
            }
          } else {
            const int ko = kb * 32 + quad8 - kinpadA;
            const unsigned short* ph = hbh + (size_t)(lA * 32 + nrow) * 512 + ko;
            const unsigned short* pl = hbl + (size_t)(lA * 32 + nrow) * 512 + ko;
            bload16(&fh0[j], ph); bload16(&fh1[j], ph + 16 * 512);
            bload16(&fl0[j], pl); bload16(&fl1[j], pl + 16 * 512);
          }
        }
      }
      bwait();

      f32x4 acc[4][2];
      #pragma unroll
      for (int g = 0; g < 4; ++g) { acc[g][0] = {0.f,0.f,0.f,0.f}; acc[g][1] = {0.f,0.f,0.f,0.f}; }

      #pragma unroll
      for (int j = 0; j < 4; ++j) {
        if (j < kbwA) {
          #pragma unroll
          for (int g = 0; g < 4; ++g) {
            acc[g][0] = MFMA16(fh0[j], wgh[j][g], acc[g][0]);
            acc[g][0] = MFMA16(fl0[j], wgh[j][g], acc[g][0]);
            acc[g][0] = MFMA16(fh0[j], wgl[j][g], acc[g][0]);
            acc[g][1] = MFMA16(fh1[j], wgh[j][g], acc[g][1]);
            acc[g][1] = MFMA16(fl1[j], wgh[j][g], acc[g][1]);
            acc[g][1] = MFMA16(fh1[j], wgl[j][g], acc[g][1]);
          }
        }
      }
      #pragma unroll
      for (int g = 0; g < 4; ++g) {
        #pragma unroll
        for (int r = 0; r < 4; ++r) {
          const int m0 = (lane >> 4) * 4 + r;
          exch[wv][g][m0 * 16 + (lane & 15)]        = acc[g][0][r];
          exch[wv][g][(m0 + 16) * 16 + (lane & 15)] = acc[g][1][r];
        }
      }
      __syncthreads();

      // ---- fused pointwise: 512 threads, 1 (b,u) each, constants in regs ----
      {
        const int e = tid, b = tid >> 4;
        float sc = 0.f, si = 0.f, sf = 0.f, so = 0.f;
        #pragma unroll
        for (int w = 0; w < 8; ++w) {
          sc += exch[w][0][e]; si += exch[w][1][e];
          sf += exch[w][2][e]; so += exch[w][3][e];
        }
        const float cin = sc + rbc;
        const float gi  = si + rbi;
        const float gf  = sf + rbf;
        const float go  = so + rbo;
        const float cx  = c_lds[e];
        const float ig  = fsig(gi + rpi * cx);
        const float fg  = fsig(gf + rpf * cx);
        float cy = fg * cx + ig * ftanh(cin);
        cy = fminf(50.0f, fmaxf(-50.0f, cy));
        const float og = fsig(go + rpo * cy);
        const float mv = og * ftanh(cy);
        c_lds[e] = cy;
        const unsigned short mh = f2bf(mv);
        const size_t mi = (size_t)(lA * 32 + b) * 1024 + uc;
        cstore1(mhi + mi, mh);
        cstore1(mlo + mi, f2bf(mv - bf2f(mh)));
      }
      __syncthreads();   // drains each wave's vm stores before flag
      if (tid == 0) {
        __hip_atomic_store(&mflag[lA * 64 + utA], (unsigned int)(s + 1),
                           __ATOMIC_RELAXED, __HIP_MEMORY_SCOPE_AGENT);
      }

      // ============ PHASE C: projection (8 waves split K, reg weights) ============
      // wait for all 64 m-producers of this layer
      if (wv == 0) {
        const unsigned int want = (unsigned int)(s + 1);
        const unsigned int* fp = mflag + lA * 64 + lane;
        while (__hip_atomic_load(fp, __ATOMIC_RELAXED, __HIP_MEMORY_SCOPE_AGENT) != want) {
          __builtin_amdgcn_s_sleep(1);
        }
      }
      __syncthreads();

      const unsigned short* mah = mhi + (size_t)(lA * 32 + mtC * 16 + nrow) * 1024;
      const unsigned short* mal = mlo + (size_t)(lA * 32 + mtC * 16 + nrow) * 1024;

      // ---- batch-issue all m-fragment loads (bypass sc1), then one wait ----
      s16x8 fmh[4], fml[4];
      #pragma unroll
      for (int j = 0; j < 4; ++j) {
        const int ko = (wv * 4 + j) * 32 + quad8;
        bload16(&fmh[j], mah + ko);
        bload16(&fml[j], mal + ko);
      }
      bwait();

      f32x4 pacc = {0.f, 0.f, 0.f, 0.f};
      #pragma unroll
      for (int j = 0; j < 4; ++j) {
        pacc = MFMA16(fmh[j], wph[j], pacc);
        pacc = MFMA16(fml[j], wph[j], pacc);
        pacc = MFMA16(fmh[j], wpl[j], pacc);
      }
      #pragma unroll
      for (int r = 0; r < 4; ++r) {
        exch[wv][0][((lane >> 4) * 4 + r) * 16 + (lane & 15)] = pacc[r];
      }
      __syncthreads();
      if (tid < 256) {
        float v = 0.f;
        #pragma unroll
        for (int w = 0; w < 8; ++w) v += exch[w][0][tid];
        const int b = mtC * 16 + (tid >> 4);
        const int p = ptC * 16 + (tid & 15);
        const size_t hidx = (size_t)wbuf * 49152 + (size_t)(lA * 32 + b) * 512 + p;
        const unsigned short hh = f2bf(v);
        cstore1(hhi + hidx, hh);
        cstore1(hlo + hidx, f2bf(v - bf2f(hh)));
        if (lA == 2) out[((size_t)t * 32 + b) * 512 + p] = v;
      }
    }
    gbar(bar, rel, seq++);
  }
}

extern "C" void kernel_launch(void* const* d_in, const int* in_sizes, int n_in,
                              void* d_out, int out_size, void* d_ws, size_t ws_size,
                              hipStream_t stream) {
  const float* x   = (const float*)d_in[0];
  const float* W0  = (const float*)d_in[1];
  const float* b0  = (const float*)d_in[2];
  const float* P0  = (const float*)d_in[3];
  const float* pi0 = (const float*)d_in[4];
  const float* pf0 = (const float*)d_in[5];
  const float* po0 = (const float*)d_in[6];
  const float* W1  = (const float*)d_in[7];
  const float* b1  = (const float*)d_in[8];
  const float* P1  = (const float*)d_in[9];
  const float* pi1 = (const float*)d_in[10];
  const float* pf1 = (const float*)d_in[11];
  const float* po1 = (const float*)d_in[12];
  const float* W2  = (const float*)d_in[13];
  const float* b2  = (const float*)d_in[14];
  const float* P2  = (const float*)d_in[15];
  const float* pi2 = (const float*)d_in[16];
  const float* pf2 = (const float*)d_in[17];
  const float* po2 = (const float*)d_in[18];

  hipLaunchKernelGGL(lstmp_persist, dim3(192), dim3(512), 0, stream,
                     x, W0, b0, P0, pi0, pf0, po0,
                     W1, b1, P1, pi1, pf1, po1,
                     W2, b2, P2, pi2, pf2, po2,
                     (float*)d_out, (unsigned char*)d_ws);
}

// Round 7
// 8106.279 us; speedup vs baseline: 2.0902x; 1.1073x over previous
//
#include <hip/hip_runtime.h>

// Persistent wavefront-pipelined LSTMP (3 layers), split-bf16 MFMA emulating fp32.
// Round 9: FAST HANDOFFS. r6 showed beat=17.9us with ~95% wait; ledger (r2/r3/r4/r6)
// eliminated HBM, read-txn rate, and barrier COUNT as causes. Remaining: per-handoff
// latency (2 structural handoffs/step). This round:
//  (1) counter-based gbar: 1 atomic add + poll of 4 spread counters (monotone),
//      removes block0 mediation (~4 LIC hops -> ~2).
//  (2) counter-based m-ready: per-layer 4-way split counter, single-line poll
//      instead of 64-line gather-poll.
//  (3) staged coalesced exchange stores: m/h -> LDS -> 16B global_store_dwordx4 sc1
//      (write-through, same visibility as atomic 2B stores) + explicit vmcnt drain.
//      1024 scattered 2B atomic ACKs -> 128 coalesced 16B ACKs per handoff.
// Reads stay r6's batched sc1 dwordx4 + single vmcnt wait. Weights register-resident.
// Numerics bit-identical (same f2bf values, same MFMA order).

typedef short s16x4 __attribute__((ext_vector_type(4)));
typedef short s16x8 __attribute__((ext_vector_type(8)));
typedef float f32x4 __attribute__((ext_vector_type(4)));

#define MFMA16(a,b,c) __builtin_amdgcn_mfma_f32_16x16x32_bf16((a),(b),(c),0,0,0)

__device__ __forceinline__ unsigned short f2bf(float f) {
  unsigned int u = __builtin_bit_cast(unsigned int, f);
  u += 0x7FFFu + ((u >> 16) & 1u);          // RNE
  return (unsigned short)(u >> 16);
}
__device__ __forceinline__ float bf2f(unsigned short h) {
  unsigned int u = ((unsigned int)h) << 16;
  return __builtin_bit_cast(float, u);
}
__device__ __forceinline__ float fsig(float x)  { return __fdividef(1.0f, 1.0f + __expf(-x)); }
__device__ __forceinline__ float ftanh(float x) { return 1.0f - __fdividef(2.0f, 1.0f + __expf(2.0f * x)); }

// Device-scope (LIC-coherent) 16B load: bypasses L1/L2 via sc1.
__device__ __forceinline__ void bload16(s16x8* dst, const unsigned short* p) {
  asm volatile("global_load_dwordx4 %0, %1, off sc1"
               : "=v"(*dst) : "v"(p) : "memory");
}
__device__ __forceinline__ void bwait() {
  asm volatile("s_waitcnt vmcnt(0)" ::: "memory");
  __builtin_amdgcn_sched_barrier(0);   // rule #18
}
// Device-scope (LIC write-through) 16B store. Needs explicit vmcnt drain.
__device__ __forceinline__ void bstore16(unsigned short* p, s16x8 v) {
  asm volatile("global_store_dwordx4 %0, %1, off sc1"
               :: "v"(p), "v"(v) : "memory");
}

__device__ __forceinline__ unsigned int cnt_load(const unsigned int* p) {
  return __hip_atomic_load(p, __ATOMIC_RELAXED, __HIP_MEMORY_SCOPE_AGENT);
}
__device__ __forceinline__ void cnt_add(unsigned int* p) {
  __hip_atomic_fetch_add(p, 1u, __ATOMIC_RELAXED, __HIP_MEMORY_SCOPE_AGENT);
}

// Legacy sense-counting grid barrier — INIT ONLY (self-correcting across runs).
__device__ __forceinline__ void gbar(unsigned int* bar, unsigned int* rel, unsigned int seq) {
  __syncthreads();
  asm volatile("" ::: "memory");
  if (blockIdx.x == 0) {
    const int tid = threadIdx.x;
    if (tid > 0 && tid < 192) {
      while (__hip_atomic_load(&bar[tid * 16], __ATOMIC_RELAXED, __HIP_MEMORY_SCOPE_AGENT) != seq) {
        __builtin_amdgcn_s_sleep(1);
      }
    }
    __syncthreads();
    if (tid == 0) {
      __hip_atomic_store(rel, seq, __ATOMIC_RELAXED, __HIP_MEMORY_SCOPE_AGENT);
    }
  } else {
    if (threadIdx.x == 0) {
      __hip_atomic_store(&bar[blockIdx.x * 16], seq, __ATOMIC_RELAXED, __HIP_MEMORY_SCOPE_AGENT);
      while (__hip_atomic_load(rel, __ATOMIC_RELAXED, __HIP_MEMORY_SCOPE_AGENT) != seq) {
        __builtin_amdgcn_s_sleep(1);
      }
    }
    __syncthreads();
  }
  asm volatile("" ::: "memory");
}

__global__ __launch_bounds__(512, 2) void lstmp_persist(
    const float* __restrict__ x,
    const float* __restrict__ W0, const float* __restrict__ b0, const float* __restrict__ P0,
    const float* __restrict__ pi0, const float* __restrict__ pf0, const float* __restrict__ po0,
    const float* __restrict__ W1, const float* __restrict__ b1, const float* __restrict__ P1,
    const float* __restrict__ pi1, const float* __restrict__ pf1, const float* __restrict__ po1,
    const float* __restrict__ W2, const float* __restrict__ b2, const float* __restrict__ P2,
    const float* __restrict__ pi2, const float* __restrict__ pf2, const float* __restrict__ po2,
    float* __restrict__ out, unsigned char* __restrict__ ws)
{
  const int tid  = threadIdx.x;
  const int bid  = blockIdx.x;
  const int lane = tid & 63;
  const int wv   = tid >> 6;             // 0..7
  const int quad8 = (lane >> 4) * 8;
  const int nrow  = lane & 15;

  // ---- workspace carve ----
  unsigned int* bar   = (unsigned int*)ws;   // init gbar: 192 slots * 16 uints
  unsigned int* rel   = bar + 4096;
  unsigned int* gcnt  = rel + 32;            // 4 counters, 128B apart (idx 0,32,64,96)
  unsigned int* mcnt  = gcnt + 128;          // 3 layers * 4 counters, 128B apart
  unsigned short* xhi = (unsigned short*)(ws + 20480);
  unsigned short* xlo  = xhi  + 4096000;   // 500*32*256
  unsigned short* hhi  = xlo  + 4096000;   // 2 bufs * 3*32*512
  unsigned short* hlo  = hhi  + 98304;
  unsigned short* mhi  = hlo  + 98304;     // 3*32*1024
  unsigned short* mlo  = mhi  + 98304;

  const float* Wsrc[3] = {W0, W1, W2};
  const float* Psrc[3] = {P0, P1, P2};
  const float* Bsrc[3] = {b0, b1, b2};
  const float* PIs[3]  = {pi0, pi1, pi2};
  const float* PFs[3]  = {pf0, pf1, pf2};
  const float* POs[3]  = {po0, po1, po2};

  __shared__ float exch[8][4][512];  // 64 KB: per-wave partial sums
  __shared__ float c_lds[512];       // persistent cell state
  __shared__ float lds_pad[4096];    // 16 KB pad -> 82 KB total -> 1 block/CU
  ((volatile float*)lds_pad)[tid & 4095] = 0.0f;  // keep it allocated
  // staging aliases inside the pad (written/read only between syncthreads)
  unsigned short* mst = (unsigned short*)lds_pad;        // 2 planes * 512
  unsigned short* hst = mst + 1024;                      // 2 planes * 256

  const unsigned int NT = 192u * 512u;
  const unsigned int gtid = (unsigned int)bid * 512u + (unsigned int)tid;

  // ---- fixed per-block roles (grid = 192, all workers) ----
  const int lA  = bid >> 6;          // layer 0..2
  const int utA = bid & 63;          // 16-unit tile (phase A)
  const int ptC = (bid & 63) >> 1;   // proj 16-col tile (phase C)
  const int mtC = bid & 1;           // batch half (phase C)

  const int nkbinA  = (lA == 0) ? 8   : 16;
  const int kinpadA = (lA == 0) ? 256 : 512;
  const int kbwA    = (lA == 0) ? 3   : 4;    // k-blocks per wave
  const int kwA     = (lA == 0) ? 752 : 1024;
  const int ninA    = (lA == 0) ? 240 : 512;
  const int kb0     = wv * kbwA;

  // ================= INIT: x staging + h zero + counter zero =================
  for (unsigned int i = gtid; i < 4096000u; i += NT) {
    unsigned int k = i & 255u, tb = i >> 8;
    float v = (k < 240u) ? x[tb * 240u + k] : 0.0f;
    unsigned short h = f2bf(v);
    xhi[i] = h; xlo[i] = f2bf(v - bf2f(h));
  }
  for (unsigned int i = gtid; i < 98304u; i += NT) { hhi[i] = 0; hlo[i] = 0; }
  for (unsigned int i = gtid; i < 640u; i += NT) gcnt[i] = 0u;  // gcnt + mcnt
  c_lds[tid] = 0.0f;

  // ================= register-resident weights =================
  s16x8 wgh[4][4], wgl[4][4];
  {
    const float* Wl = Wsrc[lA];
    #pragma unroll
    for (int j = 0; j < 4; ++j) {
      if (j < kbwA) {
        const int kbase = (kb0 + j) * 32 + quad8;
        #pragma unroll
        for (int g = 0; g < 4; ++g) {
          const size_t r = (size_t)((g * 64 + utA) * 16 + nrow);
          #pragma unroll
          for (int jj = 0; jj < 8; ++jj) {
            const int k = kbase + jj;
            float v;
            if (k < kinpadA) v = (lA == 0 && k >= 240) ? 0.0f : Wl[r * kwA + k];
            else             v = Wl[r * kwA + (k - kinpadA + ninA)];
            unsigned short h = f2bf(v);
            wgh[j][g][jj] = (short)h;
            wgl[j][g][jj] = (short)f2bf(v - bf2f(h));
          }
        }
      } else {
        #pragma unroll
        for (int g = 0; g < 4; ++g) { wgh[j][g] = (s16x8)0; wgl[j][g] = (s16x8)0; }
      }
    }
  }
  s16x8 wph[4], wpl[4];
  {
    const float* Pl = Psrc[lA];
    const size_t prow = (size_t)(ptC * 16 + nrow);
    #pragma unroll
    for (int j = 0; j < 4; ++j) {
      const int kbase = (wv * 4 + j) * 32 + quad8;
      #pragma unroll
      for (int jj = 0; jj < 8; ++jj) {
        float v = Pl[prow * 1024u + (size_t)(kbase + jj)];
        unsigned short h = f2bf(v);
        wph[j][jj] = (short)h;
        wpl[j][jj] = (short)f2bf(v - bf2f(h));
      }
    }
  }
  // Pointwise constants: this thread always handles (b=tid>>4, u=tid&15).
  const int uc = utA * 16 + (tid & 15);
  const float rbc = Bsrc[lA][uc];
  const float rbi = Bsrc[lA][1024 + uc];
  const float rbf = Bsrc[lA][2048 + uc];
  const float rbo = Bsrc[lA][3072 + uc];
  const float rpi = PIs[lA][uc];
  const float rpf = PFs[lA][uc];
  const float rpo = POs[lA][uc];

  // One-time init barrier (release fence writes back x staging + counter zeros).
  __builtin_amdgcn_fence(__ATOMIC_RELEASE, "agent");
  gbar(bar, rel, 1u);
  __builtin_amdgcn_fence(__ATOMIC_ACQUIRE, "agent");

  for (int s = 0; s < 502; ++s) {
    const int t = s - lA;
    const bool act = (t >= 0) && (t < 500);
    const int rbuf = (s + 1) & 1;    // h buffer written at step s-1
    const int wbuf = s & 1;          // h buffer written at step s

    if (act) {
      // ============ PHASE A: gates GEMM (8 waves split K, reg weights) ============
      const unsigned short* hbh = hhi + rbuf * 49152;
      const unsigned short* hbl = hlo + rbuf * 49152;

      s16x8 fh0[4], fl0[4], fh1[4], fl1[4];
      #pragma unroll
      for (int j = 0; j < 4; ++j) {
        if (j < kbwA) {
          const int kb = kb0 + j;
          if (kb < nkbinA) {
            if (lA == 0) {
              const unsigned short* ph = xhi + (size_t)(t * 32 + nrow) * 256 + kb * 32 + quad8;
              const unsigned short* pl = xlo + (size_t)(t * 32 + nrow) * 256 + kb * 32 + quad8;
              fh0[j] = *(const s16x8*)ph; fh1[j] = *(const s16x8*)(ph + 16 * 256);
              fl0[j] = *(const s16x8*)pl; fl1[j] = *(const s16x8*)(pl + 16 * 256);
            } else {
              const unsigned short* ph = hbh + (size_t)((lA - 1) * 32 + nrow) * 512 + kb * 32 + quad8;
              const unsigned short* pl = hbl + (size_t)((lA - 1) * 32 + nrow) * 512 + kb * 32 + quad8;
              bload16(&fh0[j], ph); bload16(&fh1[j], ph + 16 * 512);
              bload16(&fl0[j], pl); bload16(&fl1[j], pl + 16 * 512);
            }
          } else {
            const int ko = kb * 32 + quad8 - kinpadA;
            const unsigned short* ph = hbh + (size_t)(lA * 32 + nrow) * 512 + ko;
            const unsigned short* pl = hbl + (size_t)(lA * 32 + nrow) * 512 + ko;
            bload16(&fh0[j], ph); bload16(&fh1[j], ph + 16 * 512);
            bload16(&fl0[j], pl); bload16(&fl1[j], pl + 16 * 512);
          }
        }
      }
      bwait();

      f32x4 acc[4][2];
      #pragma unroll
      for (int g = 0; g < 4; ++g) { acc[g][0] = {0.f,0.f,0.f,0.f}; acc[g][1] = {0.f,0.f,0.f,0.f}; }

      #pragma unroll
      for (int j = 0; j < 4; ++j) {
        if (j < kbwA) {
          #pragma unroll
          for (int g = 0; g < 4; ++g) {
            acc[g][0] = MFMA16(fh0[j], wgh[j][g], acc[g][0]);
            acc[g][0] = MFMA16(fl0[j], wgh[j][g], acc[g][0]);
            acc[g][0] = MFMA16(fh0[j], wgl[j][g], acc[g][0]);
            acc[g][1] = MFMA16(fh1[j], wgh[j][g], acc[g][1]);
            acc[g][1] = MFMA16(fl1[j], wgh[j][g], acc[g][1]);
            acc[g][1] = MFMA16(fh1[j], wgl[j][g], acc[g][1]);
          }
        }
      }
      #pragma unroll
      for (int g = 0; g < 4; ++g) {
        #pragma unroll
        for (int r = 0; r < 4; ++r) {
          const int m0 = (lane >> 4) * 4 + r;
          exch[wv][g][m0 * 16 + (lane & 15)]        = acc[g][0][r];
          exch[wv][g][(m0 + 16) * 16 + (lane & 15)] = acc[g][1][r];
        }
      }
      __syncthreads();

      // ---- fused pointwise: 512 threads, 1 (b,u) each; stage m into LDS ----
      {
        const int e = tid;
        float sc = 0.f, si = 0.f, sf = 0.f, so = 0.f;
        #pragma unroll
        for (int w = 0; w < 8; ++w) {
          sc += exch[w][0][e]; si += exch[w][1][e];
          sf += exch[w][2][e]; so += exch[w][3][e];
        }
        const float cin = sc + rbc;
        const float gi  = si + rbi;
        const float gf  = sf + rbf;
        const float go  = so + rbo;
        const float cx  = c_lds[e];
        const float ig  = fsig(gi + rpi * cx);
        const float fg  = fsig(gf + rpf * cx);
        float cy = fg * cx + ig * ftanh(cin);
        cy = fminf(50.0f, fmaxf(-50.0f, cy));
        const float og = fsig(go + rpo * cy);
        const float mv = og * ftanh(cy);
        c_lds[e] = cy;
        const unsigned short mh = f2bf(mv);
        mst[e]       = mh;
        mst[512 + e] = f2bf(mv - bf2f(mh));
      }
      __syncthreads();
      // ---- coalesced 16B write-through m stores (128 threads) + drain ----
      if (tid < 128) {
        const int plane = tid >> 6;            // 0=hi, 1=lo
        const int r2 = tid & 63;
        const int bl = r2 >> 1, half = r2 & 1;
        s16x8 v = *(const s16x8*)(mst + plane * 512 + bl * 16 + half * 8);
        unsigned short* dst = (plane ? mlo : mhi) + (size_t)(lA * 32 + bl) * 1024 + utA * 16 + half * 8;
        bstore16(dst, v);
        asm volatile("s_waitcnt vmcnt(0)" ::: "memory");
      }
      __syncthreads();
      if (tid == 0) cnt_add(&mcnt[lA * 128 + (utA & 3) * 32]);

      // ============ PHASE C: projection (8 waves split K, reg weights) ============
      if (tid == 0) {
        const unsigned int want = 64u * (unsigned int)(t + 1);
        const unsigned int* mp = mcnt + lA * 128;
        for (;;) {
          unsigned int sum = cnt_load(mp) + cnt_load(mp + 32) + cnt_load(mp + 64) + cnt_load(mp + 96);
          if (sum >= want) break;
          __builtin_amdgcn_s_sleep(1);
        }
      }
      __syncthreads();

      const unsigned short* mah = mhi + (size_t)(lA * 32 + mtC * 16 + nrow) * 1024;
      const unsigned short* mal = mlo + (size_t)(lA * 32 + mtC * 16 + nrow) * 1024;

      s16x8 fmh[4], fml[4];
      #pragma unroll
      for (int j = 0; j < 4; ++j) {
        const int ko = (wv * 4 + j) * 32 + quad8;
        bload16(&fmh[j], mah + ko);
        bload16(&fml[j], mal + ko);
      }
      bwait();

      f32x4 pacc = {0.f, 0.f, 0.f, 0.f};
      #pragma unroll
      for (int j = 0; j < 4; ++j) {
        pacc = MFMA16(fmh[j], wph[j], pacc);
        pacc = MFMA16(fml[j], wph[j], pacc);
        pacc = MFMA16(fmh[j], wpl[j], pacc);
      }
      #pragma unroll
      for (int r = 0; r < 4; ++r) {
        exch[wv][0][((lane >> 4) * 4 + r) * 16 + (lane & 15)] = pacc[r];
      }
      __syncthreads();
      if (tid < 256) {
        float v = 0.f;
        #pragma unroll
        for (int w = 0; w < 8; ++w) v += exch[w][0][tid];
        const unsigned short hh = f2bf(v);
        hst[tid]       = hh;
        hst[256 + tid] = f2bf(v - bf2f(hh));
        if (lA == 2) {
          const int b = mtC * 16 + (tid >> 4);
          const int p = ptC * 16 + (tid & 15);
          out[((size_t)t * 32 + b) * 512 + p] = v;
        }
      }
      __syncthreads();
      // ---- coalesced 16B write-through h stores (64 threads) + drain ----
      if (tid < 64) {
        const int plane = tid >> 5;            // 0=hi, 1=lo
        const int r2 = tid & 31;
        const int bl = r2 >> 1, half = r2 & 1;
        s16x8 v = *(const s16x8*)(hst + plane * 256 + bl * 16 + half * 8);
        unsigned short* dst = (plane ? hlo : hhi) + (size_t)wbuf * 49152
                            + (size_t)(lA * 32 + mtC * 16 + bl) * 512 + ptC * 16 + half * 8;
        bstore16(dst, v);
        asm volatile("s_waitcnt vmcnt(0)" ::: "memory");
      }
    }
    // ============ counter-based grid barrier ============
    __syncthreads();
    if (tid == 0) {
      cnt_add(&gcnt[(bid & 3) * 32]);
      const unsigned int want = 192u * (unsigned int)(s + 1);
      for (;;) {
        unsigned int sum = cnt_load(gcnt) + cnt_load(gcnt + 32) + cnt_load(gcnt + 64) + cnt_load(gcnt + 96);
        if (sum >= want) break;
        __builtin_amdgcn_s_sleep(1);
      }
    }
    __syncthreads();
  }
}

extern "C" void kernel_launch(void* const* d_in, const int* in_sizes, int n_in,
                              void* d_out, int out_size, void* d_ws, size_t ws_size,
                              hipStream_t stream) {
  const float* x   = (const float*)d_in[0];
  const float* W0  = (const float*)d_in[1];
  const float* b0  = (const float*)d_in[2];
  const float* P0  = (const float*)d_in[3];
  const float* pi0 = (const float*)d_in[4];
  const float* pf0 = (const float*)d_in[5];
  const float* po0 = (const float*)d_in[6];
  const float* W1  = (const float*)d_in[7];
  const float* b1  = (const float*)d_in[8];
  const float* P1  = (const float*)d_in[9];
  const float* pi1 = (const float*)d_in[10];
  const float* pf1 = (const float*)d_in[11];
  const float* po1 = (const float*)d_in[12];
  const float* W2  = (const float*)d_in[13];
  const float* b2  = (const float*)d_in[14];
  const float* P2  = (const float*)d_in[15];
  const float* pi2 = (const float*)d_in[16];
  const float* pf2 = (const float*)d_in[17];
  const float* po2 = (const float*)d_in[18];

  hipLaunchKernelGGL(lstmp_persist, dim3(192), dim3(512), 0, stream,
                     x, W0, b0, P0, pi0, pf0, po0,
                     W1, b1, P1, pi1, pf1, po1,
                     W2, b2, P2, pi2, pf2, po2,
                     (float*)d_out, (unsigned char*)d_ws);
}

// Round 9
// 8025.406 us; speedup vs baseline: 2.1113x; 1.0101x over previous
//
#include <hip/hip_runtime.h>

// Persistent wavefront-pipelined LSTMP (3 layers), split-bf16 MFMA emulating fp32.
// Round 10: PER-LAYER BARRIERS. r7 beat=16.2us with ~1.75us compute, ~2-3us LIC BW,
// ~2us min sync -> ~9us residual = skew+contention of the 192-wide global barrier
// (48 serialized RMWs/counter, global slowest-block resync 2x/beat). The only true
// sync domains are per-layer (64 blocks): m-exchange and h-recurrence. This round:
//  (1) lcnt[l]: per-layer end-of-beat counter barrier (4 spread counters, 16 adds
//      each); mcnt[l] mid-beat unchanged.
//  (2) cross-layer h handoff via monotone progress polls: layer l waits
//      lcnt[l-1] >= 64*(t+1) (usually already true); h 4-slot buffered;
//      back-pressure lcnt[l+1] >= 64*(t-3) bounds drift (deadlock-free).
//  (3) init gbar made real again across graph replays: bar/rel reset at kernel end
//      (was a no-op on replays >= 2 -> counter zeroing visibility was luck).
// Reads/stores stay r7 (batched sc1 dwordx4, coalesced staged stores, reg weights).
// Numerics bit-identical (same f2bf values, same MFMA order).

typedef short s16x4 __attribute__((ext_vector_type(4)));
typedef short s16x8 __attribute__((ext_vector_type(8)));
typedef float f32x4 __attribute__((ext_vector_type(4)));

#define MFMA16(a,b,c) __builtin_amdgcn_mfma_f32_16x16x32_bf16((a),(b),(c),0,0,0)

__device__ __forceinline__ unsigned short f2bf(float f) {
  unsigned int u = __builtin_bit_cast(unsigned int, f);
  u += 0x7FFFu + ((u >> 16) & 1u);          // RNE
  return (unsigned short)(u >> 16);
}
__device__ __forceinline__ float bf2f(unsigned short h) {
  unsigned int u = ((unsigned int)h) << 16;
  return __builtin_bit_cast(float, u);
}
__device__ __forceinline__ float fsig(float x)  { return __fdividef(1.0f, 1.0f + __expf(-x)); }
__device__ __forceinline__ float ftanh(float x) { return 1.0f - __fdividef(2.0f, 1.0f + __expf(2.0f * x)); }

// Device-scope (LIC-coherent) 16B load: bypasses L1/L2 via sc1.
__device__ __forceinline__ void bload16(s16x8* dst, const unsigned short* p) {
  asm volatile("global_load_dwordx4 %0, %1, off sc1"
               : "=v"(*dst) : "v"(p) : "memory");
}
__device__ __forceinline__ void bwait() {
  asm volatile("s_waitcnt vmcnt(0)" ::: "memory");
  __builtin_amdgcn_sched_barrier(0);   // rule #18
}
// Device-scope (LIC write-through) 16B store. Needs explicit vmcnt drain.
__device__ __forceinline__ void bstore16(unsigned short* p, s16x8 v) {
  asm volatile("global_store_dwordx4 %0, %1, off sc1"
               :: "v"(p), "v"(v) : "memory");
}

__device__ __forceinline__ unsigned int cnt_load(const unsigned int* p) {
  return __hip_atomic_load(p, __ATOMIC_RELAXED, __HIP_MEMORY_SCOPE_AGENT);
}
__device__ __forceinline__ void cnt_add(unsigned int* p) {
  __hip_atomic_fetch_add(p, 1u, __ATOMIC_RELAXED, __HIP_MEMORY_SCOPE_AGENT);
}
__device__ __forceinline__ void poll4(const unsigned int* p, unsigned int want) {
  for (;;) {
    unsigned int s = cnt_load(p) + cnt_load(p + 32) + cnt_load(p + 64) + cnt_load(p + 96);
    if (s >= want) break;
    __builtin_amdgcn_s_sleep(1);
  }
}

// Legacy sense-counting grid barrier — INIT ONLY (state reset at kernel end).
__device__ __forceinline__ void gbar(unsigned int* bar, unsigned int* rel, unsigned int seq) {
  __syncthreads();
  asm volatile("" ::: "memory");
  if (blockIdx.x == 0) {
    const int tid = threadIdx.x;
    if (tid > 0 && tid < 192) {
      while (__hip_atomic_load(&bar[tid * 16], __ATOMIC_RELAXED, __HIP_MEMORY_SCOPE_AGENT) != seq) {
        __builtin_amdgcn_s_sleep(1);
      }
    }
    __syncthreads();
    if (tid == 0) {
      __hip_atomic_store(rel, seq, __ATOMIC_RELAXED, __HIP_MEMORY_SCOPE_AGENT);
    }
  } else {
    if (threadIdx.x == 0) {
      __hip_atomic_store(&bar[blockIdx.x * 16], seq, __ATOMIC_RELAXED, __HIP_MEMORY_SCOPE_AGENT);
      while (__hip_atomic_load(rel, __ATOMIC_RELAXED, __HIP_MEMORY_SCOPE_AGENT) != seq) {
        __builtin_amdgcn_s_sleep(1);
      }
    }
    __syncthreads();
  }
  asm volatile("" ::: "memory");
}

__global__ __launch_bounds__(512, 2) void lstmp_persist(
    const float* __restrict__ x,
    const float* __restrict__ W0, const float* __restrict__ b0, const float* __restrict__ P0,
    const float* __restrict__ pi0, const float* __restrict__ pf0, const float* __restrict__ po0,
    const float* __restrict__ W1, const float* __restrict__ b1, const float* __restrict__ P1,
    const float* __restrict__ pi1, const float* __restrict__ pf1, const float* __restrict__ po1,
    const float* __restrict__ W2, const float* __restrict__ b2, const float* __restrict__ P2,
    const float* __restrict__ pi2, const float* __restrict__ pf2, const float* __restrict__ po2,
    float* __restrict__ out, unsigned char* __restrict__ ws)
{
  const int tid  = threadIdx.x;
  const int bid  = blockIdx.x;
  const int lane = tid & 63;
  const int wv   = tid >> 6;             // 0..7
  const int quad8 = (lane >> 4) * 8;
  const int nrow  = lane & 15;

  // ---- workspace carve ----
  unsigned int* bar   = (unsigned int*)ws;   // init gbar: 192 slots * 16 uints
  unsigned int* rel   = bar + 4096;
  unsigned int* lcnt  = rel + 32;            // 3 layers * 4 counters, 128B apart (progress)
  unsigned int* mcnt  = lcnt + 384;          // 3 layers * 4 counters, 128B apart (mid-beat)
  unsigned short* xhi = (unsigned short*)(ws + 20480);
  unsigned short* xlo  = xhi  + 4096000;   // 500*32*256
  unsigned short* hhi  = xlo  + 4096000;   // 4 slots * 3 layers * 32*512 = 196608
  unsigned short* hlo  = hhi  + 196608;
  unsigned short* mhi  = hlo  + 196608;    // 3*32*1024
  unsigned short* mlo  = mhi  + 98304;

  const float* Wsrc[3] = {W0, W1, W2};
  const float* Psrc[3] = {P0, P1, P2};
  const float* Bsrc[3] = {b0, b1, b2};
  const float* PIs[3]  = {pi0, pi1, pi2};
  const float* PFs[3]  = {pf0, pf1, pf2};
  const float* POs[3]  = {po0, po1, po2};

  __shared__ float exch[8][4][512];  // 64 KB: per-wave partial sums
  __shared__ float c_lds[512];       // persistent cell state
  __shared__ float lds_pad[4096];    // 16 KB pad -> 82 KB total -> 1 block/CU
  ((volatile float*)lds_pad)[tid & 4095] = 0.0f;  // keep it allocated
  // staging aliases inside the pad (written/read only between syncthreads)
  unsigned short* mst = (unsigned short*)lds_pad;        // 2 planes * 512
  unsigned short* hst = mst + 1024;                      // 2 planes * 256

  const unsigned int NT = 192u * 512u;
  const unsigned int gtid = (unsigned int)bid * 512u + (unsigned int)tid;

  // ---- fixed per-block roles (grid = 192, all workers) ----
  const int lA  = bid >> 6;          // layer 0..2
  const int utA = bid & 63;          // 16-unit tile (phase A)
  const int ptC = (bid & 63) >> 1;   // proj 16-col tile (phase C)
  const int mtC = bid & 1;           // batch half (phase C)

  const int nkbinA  = (lA == 0) ? 8   : 16;
  const int kinpadA = (lA == 0) ? 256 : 512;
  const int kbwA    = (lA == 0) ? 3   : 4;    // k-blocks per wave
  const int kwA     = (lA == 0) ? 752 : 1024;
  const int ninA    = (lA == 0) ? 240 : 512;
  const int kb0     = wv * kbwA;

  // ================= INIT: x staging + h zero + counter zero =================
  for (unsigned int i = gtid; i < 4096000u; i += NT) {
    unsigned int k = i & 255u, tb = i >> 8;
    float v = (k < 240u) ? x[tb * 240u + k] : 0.0f;
    unsigned short h = f2bf(v);
    xhi[i] = h; xlo[i] = f2bf(v - bf2f(h));
  }
  for (unsigned int i = gtid; i < 196608u; i += NT) { hhi[i] = 0; hlo[i] = 0; }
  for (unsigned int i = gtid; i < 768u; i += NT) lcnt[i] = 0u;  // lcnt + mcnt
  c_lds[tid] = 0.0f;

  // ================= register-resident weights =================
  s16x8 wgh[4][4], wgl[4][4];
  {
    const float* Wl = Wsrc[lA];
    #pragma unroll
    for (int j = 0; j < 4; ++j) {
      if (j < kbwA) {
        const int kbase = (kb0 + j) * 32 + quad8;
        #pragma unroll
        for (int g = 0; g < 4; ++g) {
          const size_t r = (size_t)((g * 64 + utA) * 16 + nrow);
          #pragma unroll
          for (int jj = 0; jj < 8; ++jj) {
            const int k = kbase + jj;
            float v;
            if (k < kinpadA) v = (lA == 0 && k >= 240) ? 0.0f : Wl[r * kwA + k];
            else             v = Wl[r * kwA + (k - kinpadA + ninA)];
            unsigned short h = f2bf(v);
            wgh[j][g][jj] = (short)h;
            wgl[j][g][jj] = (short)f2bf(v - bf2f(h));
          }
        }
      } else {
        #pragma unroll
        for (int g = 0; g < 4; ++g) { wgh[j][g] = (s16x8)0; wgl[j][g] = (s16x8)0; }
      }
    }
  }
  s16x8 wph[4], wpl[4];
  {
    const float* Pl = Psrc[lA];
    const size_t prow = (size_t)(ptC * 16 + nrow);
    #pragma unroll
    for (int j = 0; j < 4; ++j) {
      const int kbase = (wv * 4 + j) * 32 + quad8;
      #pragma unroll
      for (int jj = 0; jj < 8; ++jj) {
        float v = Pl[prow * 1024u + (size_t)(kbase + jj)];
        unsigned short h = f2bf(v);
        wph[j][jj] = (short)h;
        wpl[j][jj] = (short)f2bf(v - bf2f(h));
      }
    }
  }
  // Pointwise constants: this thread always handles (b=tid>>4, u=tid&15).
  const int uc = utA * 16 + (tid & 15);
  const float rbc = Bsrc[lA][uc];
  const float rbi = Bsrc[lA][1024 + uc];
  const float rbf = Bsrc[lA][2048 + uc];
  const float rbo = Bsrc[lA][3072 + uc];
  const float rpi = PIs[lA][uc];
  const float rpf = PFs[lA][uc];
  const float rpo = POs[lA][uc];

  // One-time init barrier (release fence orders x staging + counter zeros).
  __builtin_amdgcn_fence(__ATOMIC_RELEASE, "agent");
  gbar(bar, rel, 1u);
  __builtin_amdgcn_fence(__ATOMIC_ACQUIRE, "agent");

  // ================= free-running per-layer beats, counter-coupled =================
  for (int t = 0; t < 500; ++t) {
    // ---- beat-entry waits (tid0 polls 4-spread monotone counters) ----
    if (tid == 0) {
      // own layer completed beat t-1: h[t-1] ready, m[t-1] readers done
      poll4(lcnt + lA * 128, 64u * (unsigned int)t);
      // input layer completed beat t: h_{l-1}[t] ready
      if (lA > 0) poll4(lcnt + (lA - 1) * 128, 64u * (unsigned int)(t + 1));
      // back-pressure: layer l+1 finished beat t-4 (read h slot we overwrite)
      if (lA < 2 && t >= 4) poll4(lcnt + (lA + 1) * 128, 64u * (unsigned int)(t - 3));
    }
    __syncthreads();

    const unsigned short* hRecH = hhi + (size_t)(((t + 3) & 3) * 49152 + lA * 16384);
    const unsigned short* hRecL = hlo + (size_t)(((t + 3) & 3) * 49152 + lA * 16384);
    const unsigned short* hInH  = hhi + (size_t)((t & 3) * 49152 + (lA - 1) * 16384);
    const unsigned short* hInL  = hlo + (size_t)((t & 3) * 49152 + (lA - 1) * 16384);

    // ============ PHASE A: gates GEMM (8 waves split K, reg weights) ============
    s16x8 fh0[4], fl0[4], fh1[4], fl1[4];
    #pragma unroll
    for (int j = 0; j < 4; ++j) {
      if (j < kbwA) {
        const int kb = kb0 + j;
        if (kb < nkbinA) {
          if (lA == 0) {
            const unsigned short* ph = xhi + (size_t)(t * 32 + nrow) * 256 + kb * 32 + quad8;
            const unsigned short* pl = xlo + (size_t)(t * 32 + nrow) * 256 + kb * 32 + quad8;
            fh0[j] = *(const s16x8*)ph; fh1[j] = *(const s16x8*)(ph + 16 * 256);
            fl0[j] = *(const s16x8*)pl; fl1[j] = *(const s16x8*)(pl + 16 * 256);
          } else {
            const unsigned short* ph = hInH + (size_t)nrow * 512 + kb * 32 + quad8;
            const unsigned short* pl = hInL + (size_t)nrow * 512 + kb * 32 + quad8;
            bload16(&fh0[j], ph); bload16(&fh1[j], ph + 16 * 512);
            bload16(&fl0[j], pl); bload16(&fl1[j], pl + 16 * 512);
          }
        } else {
          const int ko = kb * 32 + quad8 - kinpadA;
          const unsigned short* ph = hRecH + (size_t)nrow * 512 + ko;
          const unsigned short* pl = hRecL + (size_t)nrow * 512 + ko;
          bload16(&fh0[j], ph); bload16(&fh1[j], ph + 16 * 512);
          bload16(&fl0[j], pl); bload16(&fl1[j], pl + 16 * 512);
        }
      }
    }
    bwait();

    f32x4 acc[4][2];
    #pragma unroll
    for (int g = 0; g < 4; ++g) { acc[g][0] = {0.f,0.f,0.f,0.f}; acc[g][1] = {0.f,0.f,0.f,0.f}; }

    #pragma unroll
    for (int j = 0; j < 4; ++j) {
      if (j < kbwA) {
        #pragma unroll
        for (int g = 0; g < 4; ++g) {
          acc[g][0] = MFMA16(fh0[j], wgh[j][g], acc[g][0]);
          acc[g][0] = MFMA16(fl0[j], wgh[j][g], acc[g][0]);
          acc[g][0] = MFMA16(fh0[j], wgl[j][g], acc[g][0]);
          acc[g][1] = MFMA16(fh1[j], wgh[j][g], acc[g][1]);
          acc[g][1] = MFMA16(fl1[j], wgh[j][g], acc[g][1]);
          acc[g][1] = MFMA16(fh1[j], wgl[j][g], acc[g][1]);
        }
      }
    }
    #pragma unroll
    for (int g = 0; g < 4; ++g) {
      #pragma unroll
      for (int r = 0; r < 4; ++r) {
        const int m0 = (lane >> 4) * 4 + r;
        exch[wv][g][m0 * 16 + (lane & 15)]        = acc[g][0][r];
        exch[wv][g][(m0 + 16) * 16 + (lane & 15)] = acc[g][1][r];
      }
    }
    __syncthreads();

    // ---- fused pointwise: 512 threads, 1 (b,u) each; stage m into LDS ----
    {
      const int e = tid;
      float sc = 0.f, si = 0.f, sf = 0.f, so = 0.f;
      #pragma unroll
      for (int w = 0; w < 8; ++w) {
        sc += exch[w][0][e]; si += exch[w][1][e];
        sf += exch[w][2][e]; so += exch[w][3][e];
      }
      const float cin = sc + rbc;
      const float gi  = si + rbi;
      const float gf  = sf + rbf;
      const float go  = so + rbo;
      const float cx  = c_lds[e];
      const float ig  = fsig(gi + rpi * cx);
      const float fg  = fsig(gf + rpf * cx);
      float cy = fg * cx + ig * ftanh(cin);
      cy = fminf(50.0f, fmaxf(-50.0f, cy));
      const float og = fsig(go + rpo * cy);
      const float mv = og * ftanh(cy);
      c_lds[e] = cy;
      const unsigned short mh = f2bf(mv);
      mst[e]       = mh;
      mst[512 + e] = f2bf(mv - bf2f(mh));
    }
    __syncthreads();
    // ---- coalesced 16B write-through m stores (128 threads) + drain ----
    if (tid < 128) {
      const int plane = tid >> 6;            // 0=hi, 1=lo
      const int r2 = tid & 63;
      const int bl = r2 >> 1, half = r2 & 1;
      s16x8 v = *(const s16x8*)(mst + plane * 512 + bl * 16 + half * 8);
      unsigned short* dst = (plane ? mlo : mhi) + (size_t)(lA * 32 + bl) * 1024 + utA * 16 + half * 8;
      bstore16(dst, v);
      asm volatile("s_waitcnt vmcnt(0)" ::: "memory");
    }
    __syncthreads();
    if (tid == 0) {
      cnt_add(&mcnt[lA * 128 + (utA & 3) * 32]);
      // wait for all 64 m-producers of this layer at beat t
      poll4(mcnt + lA * 128, 64u * (unsigned int)(t + 1));
    }
    __syncthreads();

    // ============ PHASE C: projection (8 waves split K, reg weights) ============
    const unsigned short* mah = mhi + (size_t)(lA * 32 + mtC * 16 + nrow) * 1024;
    const unsigned short* mal = mlo + (size_t)(lA * 32 + mtC * 16 + nrow) * 1024;

    s16x8 fmh[4], fml[4];
    #pragma unroll
    for (int j = 0; j < 4; ++j) {
      const int ko = (wv * 4 + j) * 32 + quad8;
      bload16(&fmh[j], mah + ko);
      bload16(&fml[j], mal + ko);
    }
    bwait();

    f32x4 pacc = {0.f, 0.f, 0.f, 0.f};
    #pragma unroll
    for (int j = 0; j < 4; ++j) {
      pacc = MFMA16(fmh[j], wph[j], pacc);
      pacc = MFMA16(fml[j], wph[j], pacc);
      pacc = MFMA16(fmh[j], wpl[j], pacc);
    }
    #pragma unroll
    for (int r = 0; r < 4; ++r) {
      exch[wv][0][((lane >> 4) * 4 + r) * 16 + (lane & 15)] = pacc[r];
    }
    __syncthreads();
    if (tid < 256) {
      float v = 0.f;
      #pragma unroll
      for (int w = 0; w < 8; ++w) v += exch[w][0][tid];
      const unsigned short hh = f2bf(v);
      hst[tid]       = hh;
      hst[256 + tid] = f2bf(v - bf2f(hh));
      if (lA == 2) {
        const int b = mtC * 16 + (tid >> 4);
        const int p = ptC * 16 + (tid & 15);
        out[((size_t)t * 32 + b) * 512 + p] = v;
      }
    }
    __syncthreads();
    // ---- coalesced 16B write-through h stores (64 threads) + drain ----
    if (tid < 64) {
      const int plane = tid >> 5;            // 0=hi, 1=lo
      const int r2 = tid & 31;
      const int bl = r2 >> 1, half = r2 & 1;
      s16x8 v = *(const s16x8*)(hst + plane * 256 + bl * 16 + half * 8);
      unsigned short* dst = (plane ? hlo : hhi) + (size_t)((t & 3) * 49152 + lA * 16384)
                          + (size_t)(mtC * 16 + bl) * 512 + ptC * 16 + half * 8;
      bstore16(dst, v);
      asm volatile("s_waitcnt vmcnt(0)" ::: "memory");
    }
    __syncthreads();
    if (tid == 0) cnt_add(&lcnt[lA * 128 + (utA & 3) * 32]);
  }

  // ---- reset legacy init-gbar state so next graph replay's init sync is real ----
  __syncthreads();
  if (tid == 0) {
    __hip_atomic_store(&bar[bid * 16], 0u, __ATOMIC_RELAXED, __HIP_MEMORY_SCOPE_AGENT);
    if (bid == 0) __hip_atomic_store(rel, 0u, __ATOMIC_RELAXED, __HIP_MEMORY_SCOPE_AGENT);
  }
}

extern "C" void kernel_launch(void* const* d_in, const int* in_sizes, int n_in,
                              void* d_out, int out_size, void* d_ws, size_t ws_size,
                              hipStream_t stream) {
  const float* x   = (const float*)d_in[0];
  const float* W0  = (const float*)d_in[1];
  const float* b0  = (const float*)d_in[2];
  const float* P0  = (const float*)d_in[3];
  const float* pi0 = (const float*)d_in[4];
  const float* pf0 = (const float*)d_in[5];
  const float* po0 = (const float*)d_in[6];
  const float* W1  = (const float*)d_in[7];
  const float* b1  = (const float*)d_in[8];
  const float* P1  = (const float*)d_in[9];
  const float* pi1 = (const float*)d_in[10];
  const float* pf1 = (const float*)d_in[11];
  const float* po1 = (const float*)d_in[12];
  const float* W2  = (const float*)d_in[13];
  const float* b2  = (const float*)d_in[14];
  const float* P2  = (const float*)d_in[15];
  const float* pi2 = (const float*)d_in[16];
  const float* pf2 = (const float*)d_in[17];
  const float* po2 = (const float*)d_in[18];

  hipLaunchKernelGGL(lstmp_persist, dim3(192), dim3(512), 0, stream,
                     x, W0, b0, P0, pi0, pf0, po0,
                     W1, b1, P1, pi1, pf1, po1,
                     W2, b2, P2, pi2, pf2, po2,
                     (float*)d_out, (unsigned char*)d_ws);
}